// Round 4
// baseline (1345.199 us; speedup 1.0000x reference)
//
#include <hip/hip_runtime.h>

#define N_VOX 200000
#define NPAD_INV (27 * N_VOX + 128)
#define EPS_BN 1e-5f

typedef __bf16 bf16x8 __attribute__((ext_vector_type(8)));
typedef float f32x4 __attribute__((ext_vector_type(4)));

__device__ __forceinline__ float bf2f(unsigned short u) {
    union { float f; unsigned int i; } x; x.i = ((unsigned int)u) << 16; return x.f;
}
__device__ __forceinline__ unsigned short f2bf(float f) {
    union { float f; unsigned int i; } x; x.f = f;
    unsigned int r = x.i + 0x7fffu + ((x.i >> 16) & 1u);  // RNE
    return (unsigned short)(r >> 16);
}

// async 16B/lane global->LDS; LDS dest = wave-uniform base + lane*16
#define ASYNC16(gsrc, ldst)                                                             \
    __builtin_amdgcn_global_load_lds(                                                   \
        (const __attribute__((address_space(1))) void*)(gsrc),                          \
        (__attribute__((address_space(3))) void*)(ldst), 16, 0, 0)

// ---------------- prep0: fill_inv + tr_wn + (feats -> fRaw cast + BN1 stats) -----------
__global__ void prep0_kernel(const float* __restrict__ feats, const float* __restrict__ w_nin,
                             int* __restrict__ inv, unsigned short* __restrict__ w_nint,
                             unsigned short* __restrict__ fRaw,
                             float* __restrict__ s1sum, float* __restrict__ s1sq) {
    __shared__ float rs[64], rq[64];
    const int t = threadIdx.x;
    if (t < 64) { rs[t] = 0.f; rq[t] = 0.f; }
    __syncthreads();
    const int stride = gridDim.x * 256;
    for (int i = blockIdx.x * 256 + t; i < NPAD_INV; i += stride) inv[i] = N_VOX;
    for (int i = blockIdx.x * 256 + t; i < 8192; i += stride) {
        int a = i >> 7, b = i & 127;
        w_nint[b * 64 + a] = f2bf(w_nin[i]);
    }
    // fused: read feats once -> bf16 cast + per-channel sum/sumsq
    float s[8] = {}, q[8] = {};
    const int total = N_VOX * 64 / 8;
    for (int i = blockIdx.x * 256 + t; i < total; i += stride) {
        const float4* src = (const float4*)(feats + (size_t)i * 8);
        float4 f0 = src[0], f1 = src[1];
        float fv[8] = {f0.x, f0.y, f0.z, f0.w, f1.x, f1.y, f1.z, f1.w};
        union { uint4 u4; unsigned short u[8]; } r;
#pragma unroll
        for (int j = 0; j < 8; j++) {
            r.u[j] = f2bf(fv[j]);
            s[j] += fv[j]; q[j] += fv[j] * fv[j];
        }
        *(uint4*)(fRaw + (size_t)i * 8) = r.u4;
    }
    // lane's channel block = (lane&7)*8 (stride multiple of 8 chunks keeps it fixed)
#pragma unroll
    for (int j = 0; j < 8; j++) {
        s[j] += __shfl_xor(s[j], 8, 64); s[j] += __shfl_xor(s[j], 16, 64); s[j] += __shfl_xor(s[j], 32, 64);
        q[j] += __shfl_xor(q[j], 8, 64); q[j] += __shfl_xor(q[j], 16, 64); q[j] += __shfl_xor(q[j], 32, 64);
    }
    const int lane = t & 63;
    if (lane < 8) {
#pragma unroll
        for (int j = 0; j < 8; j++) {
            atomicAdd(&rs[lane * 8 + j], s[j]);
            atomicAdd(&rq[lane * 8 + j], q[j]);
        }
    }
    __syncthreads();
    if (t < 64) { atomicAdd(&s1sum[t], rs[t]); atomicAdd(&s1sq[t], rq[t]); }
}

// ---------------- inverse kernel-map ----------------
__global__ void build_inv_kernel(const int* __restrict__ sidx, const int* __restrict__ gidx,
                                 int* __restrict__ inv) {
    int k = blockIdx.y;
    int p = blockIdx.x * 256 + threadIdx.x;
    if (p < N_VOX) {
        int s = sidx[k * N_VOX + p];
        if (s < N_VOX) inv[k * N_VOX + s] = gidx[k * N_VOX + p];  // unique s per k -> no race
    }
}

// ---- prep1: BN1 folded weights: w1t[k][n][a] = bf16(w1[k][a][n]*sc1[a]); T1[k][n]=sh1@W1[k]
__global__ void prep1_kernel(const float* __restrict__ w1, const float* __restrict__ s1sum,
                             const float* __restrict__ s1sq, const float* __restrict__ g1,
                             const float* __restrict__ b1, unsigned short* __restrict__ w1t,
                             float* __restrict__ T1g) {
    __shared__ float lsc[64], lsh[64];
    const int t = threadIdx.x;
    if (t < 64) {
        float mean = s1sum[t] * (1.0f / N_VOX);
        float var  = s1sq[t] * (1.0f / N_VOX) - mean * mean;
        float sc   = g1[t] * rsqrtf(var + EPS_BN);
        lsc[t] = sc; lsh[t] = b1[t] - mean * sc;
    }
    __syncthreads();
    const int stride = gridDim.x * 256;
    for (int e = blockIdx.x * 256 + t; e < 27 * 8192; e += stride) {
        int k = e >> 13, idx = e & 8191;
        int a = idx >> 7, n = idx & 127;
        w1t[k * 8192 + n * 64 + a] = f2bf(w1[e] * lsc[a]);
    }
    int o = blockIdx.x * 256 + t;
    if (o < 27 * 128) {
        int k = o >> 7, n = o & 127;
        float sacc = 0.f;
        for (int a = 0; a < 64; a++) sacc += lsh[a] * w1[k * 8192 + a * 128 + n];
        T1g[o] = sacc;
    }
}

// ---- prep2: BN2 folded: w2t[k][n][a] = bf16(w2[k][a][n]*sc2[a]); T2[k][n]=sh2@W2[k]
__global__ void prep2_kernel(const float* __restrict__ w2, const float* __restrict__ s2sum,
                             const float* __restrict__ s2sq, const float* __restrict__ g2,
                             const float* __restrict__ b2, unsigned short* __restrict__ w2t,
                             float* __restrict__ T2g) {
    __shared__ float lsc[128], lsh[128];
    const int t = threadIdx.x;
    if (t < 128) {
        float mean = s2sum[t] * (1.0f / N_VOX);
        float var  = s2sq[t] * (1.0f / N_VOX) - mean * mean;
        float sc   = g2[t] * rsqrtf(var + EPS_BN);
        lsc[t] = sc; lsh[t] = b2[t] - mean * sc;
    }
    __syncthreads();
    const int stride = gridDim.x * 256;
    for (int e = blockIdx.x * 256 + t; e < 27 * 16384; e += stride) {
        int k = e >> 14, idx = e & 16383;
        int a = idx >> 7, n = idx & 127;
        w2t[k * 16384 + n * 128 + a] = f2bf(w2[e] * lsc[a]);
    }
    int o = blockIdx.x * 256 + t;
    if (o < 27 * 128) {
        int k = o >> 7, n = o & 127;
        float sacc = 0.f;
        for (int a = 0; a < 128; a++) sacc += lsh[a] * w2[k * 16384 + a * 128 + n];
        T2g[o] = sacc;
    }
}

// ---------------- conv1: h1[i] = sum_k BN1(f)[inv[k][i]] @ w1[k]  (64->128, bf16 out) ------
// R2-proven pipeline (2-deep dbuf, counted vmcnt(8), 2 barriers/iter, T2 swizzle). BN1 is
// folded: A = raw feats (bf16), w1t pre-scaled by sc1, presence-dependent bias
// sum_{k present} sh1@W1[k] added in epilogue via per-row bitmask recorded during staging.
// BN2 stats (sum/sumsq of fp32 h1) fused into the epilogue (free under the gather wall).
__global__ __launch_bounds__(256) void conv1_kernel(
    const unsigned short* __restrict__ fRaw, const unsigned short* __restrict__ w1t,
    const int* __restrict__ inv, const unsigned short* __restrict__ zp,
    const float* __restrict__ T1g, unsigned short* __restrict__ h1b,
    float* __restrict__ s2sum, float* __restrict__ s2sq) {
    __shared__ __align__(16) unsigned short sA[2][128 * 64];
    __shared__ __align__(16) unsigned short sB[2][128 * 64];
    __shared__ unsigned int presmask[128];
    __shared__ float s2s[128], s2q[128];
    const int t = threadIdx.x, lane = t & 63, w = t >> 6;
    const int v0 = blockIdx.x * 128;
    const int srow = w * 32;
    const int lrow = lane >> 3;
    const int lcol = (lane & 7) * 8;
    const int scol = lcol ^ (lrow * 8);
    const int m0 = (w & 1) * 64, n0 = (w >> 1) * 64;
    const int l16 = lane & 15, quad = lane >> 4;
    const int xs = l16 & 7;
    f32x4 acc[4][4] = {};

    if (t < 128) { presmask[t] = 0u; s2s[t] = 0.f; s2q[t] = 0.f; }
    __syncthreads();

    auto stage = [&](int k, int b) {
#pragma unroll
        for (int q = 0; q < 4; q++) {
            int rt = srow + q * 8 + lrow;
            int g = inv[k * N_VOX + v0 + rt];
            if ((lane & 7) == 0 && g < N_VOX) atomicOr(&presmask[rt], 1u << k);
            const unsigned short* asrc = (g < N_VOX) ? (fRaw + (size_t)g * 64 + scol) : (zp + scol);
            ASYNC16(asrc, &sA[b][(srow + q * 8) * 64]);
            const unsigned short* bsrc = w1t + k * 8192 + rt * 64 + scol;
            ASYNC16(bsrc, &sB[b][(srow + q * 8) * 64]);
        }
    };

    stage(0, 0);
    for (int j = 0; j < 27; j++) {
        const int cb = j & 1;
        if (j + 1 < 27) {
            stage(j + 1, cb ^ 1);
            asm volatile("s_waitcnt vmcnt(8)" ::: "memory");
        } else {
            asm volatile("s_waitcnt vmcnt(0)" ::: "memory");
        }
        __builtin_amdgcn_sched_barrier(0);
        __builtin_amdgcn_s_barrier();
        __builtin_amdgcn_sched_barrier(0);
#pragma unroll
        for (int ks = 0; ks < 2; ks++) {
            const int cs = ((ks * 4 + quad) ^ xs) * 8;
            bf16x8 af[4], bfr[4];
#pragma unroll
            for (int mi = 0; mi < 4; mi++)
                af[mi] = *(const bf16x8*)&sA[cb][(m0 + mi * 16 + l16) * 64 + cs];
#pragma unroll
            for (int ni = 0; ni < 4; ni++)
                bfr[ni] = *(const bf16x8*)&sB[cb][(n0 + ni * 16 + l16) * 64 + cs];
            __builtin_amdgcn_s_setprio(1);
#pragma unroll
            for (int mi = 0; mi < 4; mi++)
#pragma unroll
                for (int ni = 0; ni < 4; ni++)
                    acc[mi][ni] = __builtin_amdgcn_mfma_f32_16x16x32_bf16(af[mi], bfr[ni], acc[mi][ni], 0, 0, 0);
            __builtin_amdgcn_s_setprio(0);
        }
        __builtin_amdgcn_sched_barrier(0);
        __builtin_amdgcn_s_barrier();
        __builtin_amdgcn_sched_barrier(0);
    }

    // ---- epilogue: presence bias + fused BN2 stats + bf16 store ----
    float* Tl = (float*)&sA[0][0];
    for (int idx = t; idx < 27 * 128; idx += 256) Tl[idx] = T1g[idx];
    __syncthreads();

    unsigned int rm[16];
#pragma unroll
    for (int mi = 0; mi < 4; mi++)
#pragma unroll
        for (int r = 0; r < 4; r++)
            rm[mi * 4 + r] = presmask[m0 + mi * 16 + quad * 4 + r];
    for (int k = 0; k < 27; k++) {
        float tk0 = Tl[k * 128 + n0 + l16];
        float tk1 = Tl[k * 128 + n0 + 16 + l16];
        float tk2 = Tl[k * 128 + n0 + 32 + l16];
        float tk3 = Tl[k * 128 + n0 + 48 + l16];
#pragma unroll
        for (int mi = 0; mi < 4; mi++)
#pragma unroll
            for (int r = 0; r < 4; r++)
                if ((rm[mi * 4 + r] >> k) & 1u) {
                    acc[mi][0][r] += tk0; acc[mi][1][r] += tk1;
                    acc[mi][2][r] += tk2; acc[mi][3][r] += tk3;
                }
    }
    float ps[4] = {}, pq[4] = {};
#pragma unroll
    for (int mi = 0; mi < 4; mi++)
#pragma unroll
        for (int r = 0; r < 4; r++) {
            int v = v0 + m0 + mi * 16 + quad * 4 + r;
            if (v < N_VOX) {
#pragma unroll
                for (int ni = 0; ni < 4; ni++) {
                    float x = acc[mi][ni][r];
                    ps[ni] += x; pq[ni] += x * x;
                    h1b[(size_t)v * 128 + n0 + ni * 16 + l16] = f2bf(x);
                }
            }
        }
#pragma unroll
    for (int ni = 0; ni < 4; ni++) {
        ps[ni] += __shfl_xor(ps[ni], 16, 64); ps[ni] += __shfl_xor(ps[ni], 32, 64);
        pq[ni] += __shfl_xor(pq[ni], 16, 64); pq[ni] += __shfl_xor(pq[ni], 32, 64);
    }
    if (lane < 16) {
#pragma unroll
        for (int ni = 0; ni < 4; ni++) {
            atomicAdd(&s2s[n0 + ni * 16 + lane], ps[ni]);
            atomicAdd(&s2q[n0 + ni * 16 + lane], pq[ni]);
        }
    }
    __syncthreads();
    if (t < 128) { atomicAdd(&s2sum[t], s2s[t]); atomicAdd(&s2sq[t], s2q[t]); }
}

// ------- conv2 + skip: out = sum_k BN2(h1)[inv[k]] @ w2[k] + fRaw @ w_nin (fp32 out) -------
// BN2 folded: gathers raw h1b, w2t pre-scaled by sc2, presence bias T2 in epilogue.
// 55 BK=64 iters: jj<54 -> (ko=jj>>1, kh=jj&1); jj==54 -> fused 1x1 skip. norm2 eliminated.
__global__ __launch_bounds__(256) void conv2_kernel(
    const unsigned short* __restrict__ h1n, const unsigned short* __restrict__ fRaw,
    const unsigned short* __restrict__ w2t, const unsigned short* __restrict__ w_nint,
    const int* __restrict__ inv, const unsigned short* __restrict__ zp,
    const float* __restrict__ T2g, float* __restrict__ out) {
    __shared__ __align__(16) unsigned short sA[2][128 * 64];
    __shared__ __align__(16) unsigned short sB[2][128 * 64];
    __shared__ unsigned int presmask[128];
    const int t = threadIdx.x, lane = t & 63, w = t >> 6;
    const int v0 = blockIdx.x * 128;
    const int srow = w * 32;
    const int lrow = lane >> 3;
    const int lcol = (lane & 7) * 8;
    const int scol = lcol ^ (lrow * 8);
    const int m0 = (w & 1) * 64, n0 = (w >> 1) * 64;
    const int l16 = lane & 15, quad = lane >> 4;
    const int xs = l16 & 7;
    f32x4 acc[4][4] = {};

    if (t < 128) presmask[t] = 0u;
    __syncthreads();

    auto stage = [&](int j, int b) {
        if (j < 54) {
            const int ko = j >> 1;
            const int kh = (j & 1) * 64;
#pragma unroll
            for (int q = 0; q < 4; q++) {
                int rt = srow + q * 8 + lrow;
                int g = inv[ko * N_VOX + v0 + rt];
                if ((j & 1) == 0 && (lane & 7) == 0 && g < N_VOX) atomicOr(&presmask[rt], 1u << ko);
                const unsigned short* asrc = (g < N_VOX) ? (h1n + (size_t)g * 128 + kh + scol) : (zp + scol);
                ASYNC16(asrc, &sA[b][(srow + q * 8) * 64]);
                const unsigned short* bsrc = w2t + ko * 16384 + rt * 128 + kh + scol;
                ASYNC16(bsrc, &sB[b][(srow + q * 8) * 64]);
            }
        } else {
#pragma unroll
            for (int q = 0; q < 4; q++) {
                int rt = srow + q * 8 + lrow;
                int v = v0 + rt;
                const unsigned short* asrc = (v < N_VOX) ? (fRaw + (size_t)v * 64 + scol) : (zp + scol);
                ASYNC16(asrc, &sA[b][(srow + q * 8) * 64]);
                const unsigned short* bsrc = w_nint + rt * 64 + scol;
                ASYNC16(bsrc, &sB[b][(srow + q * 8) * 64]);
            }
        }
    };

    stage(0, 0);
    for (int jj = 0; jj < 55; jj++) {
        const int cb = jj & 1;
        if (jj + 1 < 55) {
            stage(jj + 1, cb ^ 1);
            asm volatile("s_waitcnt vmcnt(8)" ::: "memory");
        } else {
            asm volatile("s_waitcnt vmcnt(0)" ::: "memory");
        }
        __builtin_amdgcn_sched_barrier(0);
        __builtin_amdgcn_s_barrier();
        __builtin_amdgcn_sched_barrier(0);
#pragma unroll
        for (int ks = 0; ks < 2; ks++) {
            const int cs = ((ks * 4 + quad) ^ xs) * 8;
            bf16x8 af[4], bfr[4];
#pragma unroll
            for (int mi = 0; mi < 4; mi++)
                af[mi] = *(const bf16x8*)&sA[cb][(m0 + mi * 16 + l16) * 64 + cs];
#pragma unroll
            for (int ni = 0; ni < 4; ni++)
                bfr[ni] = *(const bf16x8*)&sB[cb][(n0 + ni * 16 + l16) * 64 + cs];
            __builtin_amdgcn_s_setprio(1);
#pragma unroll
            for (int mi = 0; mi < 4; mi++)
#pragma unroll
                for (int ni = 0; ni < 4; ni++)
                    acc[mi][ni] = __builtin_amdgcn_mfma_f32_16x16x32_bf16(af[mi], bfr[ni], acc[mi][ni], 0, 0, 0);
            __builtin_amdgcn_s_setprio(0);
        }
        __builtin_amdgcn_sched_barrier(0);
        __builtin_amdgcn_s_barrier();
        __builtin_amdgcn_sched_barrier(0);
    }

    // ---- epilogue: presence bias (T2) + fp32 store ----
    float* Tl = (float*)&sA[0][0];
    for (int idx = t; idx < 27 * 128; idx += 256) Tl[idx] = T2g[idx];
    __syncthreads();

    unsigned int rm[16];
#pragma unroll
    for (int mi = 0; mi < 4; mi++)
#pragma unroll
        for (int r = 0; r < 4; r++)
            rm[mi * 4 + r] = presmask[m0 + mi * 16 + quad * 4 + r];
    for (int k = 0; k < 27; k++) {
        float tk0 = Tl[k * 128 + n0 + l16];
        float tk1 = Tl[k * 128 + n0 + 16 + l16];
        float tk2 = Tl[k * 128 + n0 + 32 + l16];
        float tk3 = Tl[k * 128 + n0 + 48 + l16];
#pragma unroll
        for (int mi = 0; mi < 4; mi++)
#pragma unroll
            for (int r = 0; r < 4; r++)
                if ((rm[mi * 4 + r] >> k) & 1u) {
                    acc[mi][0][r] += tk0; acc[mi][1][r] += tk1;
                    acc[mi][2][r] += tk2; acc[mi][3][r] += tk3;
                }
    }
#pragma unroll
    for (int mi = 0; mi < 4; mi++)
#pragma unroll
        for (int r = 0; r < 4; r++) {
            int v = v0 + m0 + mi * 16 + quad * 4 + r;
            if (v < N_VOX) {
#pragma unroll
                for (int ni = 0; ni < 4; ni++)
                    out[(size_t)v * 128 + n0 + ni * 16 + l16] = acc[mi][ni][r];
            }
        }
}

extern "C" void kernel_launch(void* const* d_in, const int* in_sizes, int n_in,
                              void* d_out, int out_size, void* d_ws, size_t ws_size,
                              hipStream_t stream) {
    const float* feats = (const float*)d_in[0];
    const float* w1    = (const float*)d_in[1];
    const float* w2    = (const float*)d_in[2];
    const float* w_nin = (const float*)d_in[3];
    const float* g1    = (const float*)d_in[4];
    const float* b1    = (const float*)d_in[5];
    const float* g2    = (const float*)d_in[6];
    const float* b2    = (const float*)d_in[7];
    const int* gidx = (const int*)d_in[8];
    const int* sidx = (const int*)d_in[9];
    float* out = (float*)d_out;

    // workspace layout (~99.8 MB, 16B-aligned)
    char* ws = (char*)d_ws;
    int* inv               = (int*)(ws);                          // 21,600,512
    unsigned short* fRaw   = (unsigned short*)(ws + 21600512);    // 25,600,000
    unsigned short* h1b    = (unsigned short*)(ws + 47200512);    // 51,200,000
    unsigned short* w1t    = (unsigned short*)(ws + 98400512);    // 442,368
    unsigned short* w2t    = (unsigned short*)(ws + 98842880);    // 884,736
    unsigned short* w_nint = (unsigned short*)(ws + 99727616);    // 16,384
    float* T1g             = (float*)(ws + 99744000);             // 13,824
    float* T2g             = (float*)(ws + 99757824);             // 13,824
    float* stats           = (float*)(ws + 99771648);             // 1,536
    unsigned short* zp     = (unsigned short*)(ws + 99773184);    // 256 (zero page)
    float* s1sum = stats, *s1sq = stats + 64, *s2sum = stats + 128, *s2sq = stats + 256;

    hipMemsetAsync(stats, 0, 1536 + 256, stream);  // stats + zero page
    prep0_kernel<<<1024, 256, 0, stream>>>(feats, w_nin, inv, w_nint, fRaw, s1sum, s1sq);
    build_inv_kernel<<<dim3(782, 27), 256, 0, stream>>>(sidx, gidx, inv);
    prep1_kernel<<<512, 256, 0, stream>>>(w1, s1sum, s1sq, g1, b1, w1t, T1g);
    conv1_kernel<<<1563, 256, 0, stream>>>(fRaw, w1t, inv, zp, T1g, h1b, s2sum, s2sq);
    prep2_kernel<<<512, 256, 0, stream>>>(w2, s2sum, s2sq, g2, b2, w2t, T2g);
    conv2_kernel<<<1563, 256, 0, stream>>>(h1b, fRaw, w2t, w_nint, inv, zp, T2g, out);
}

// Round 5
// 971.508 us; speedup vs baseline: 1.3846x; 1.3846x over previous
//
#include <hip/hip_runtime.h>

#define N_VOX 200000
#define NPAD_INV (27 * N_VOX + 128)
#define EPS_BN 1e-5f

typedef __bf16 bf16x8 __attribute__((ext_vector_type(8)));
typedef float f32x4 __attribute__((ext_vector_type(4)));

__device__ __forceinline__ float bf2f(unsigned short u) {
    union { float f; unsigned int i; } x; x.i = ((unsigned int)u) << 16; return x.f;
}
__device__ __forceinline__ unsigned short f2bf(float f) {
    union { float f; unsigned int i; } x; x.f = f;
    unsigned int r = x.i + 0x7fffu + ((x.i >> 16) & 1u);  // RNE
    return (unsigned short)(r >> 16);
}

// async 16B/lane global->LDS; LDS dest = wave-uniform base + lane*16
#define ASYNC16(gsrc, ldst)                                                             \
    __builtin_amdgcn_global_load_lds(                                                   \
        (const __attribute__((address_space(1))) void*)(gsrc),                          \
        (__attribute__((address_space(3))) void*)(ldst), 16, 0, 0)

// ---------------- prep0: fill_inv + tr_wn + (feats -> fRaw cast + BN1 stats) -----------
__global__ void prep0_kernel(const float* __restrict__ feats, const float* __restrict__ w_nin,
                             int* __restrict__ inv, unsigned short* __restrict__ w_nint,
                             unsigned short* __restrict__ fRaw,
                             float* __restrict__ s1sum, float* __restrict__ s1sq) {
    __shared__ float rs[64], rq[64];
    const int t = threadIdx.x;
    if (t < 64) { rs[t] = 0.f; rq[t] = 0.f; }
    __syncthreads();
    const int stride = gridDim.x * 256;
    for (int i = blockIdx.x * 256 + t; i < NPAD_INV; i += stride) inv[i] = N_VOX;
    for (int i = blockIdx.x * 256 + t; i < 8192; i += stride) {
        int a = i >> 7, b = i & 127;
        w_nint[b * 64 + a] = f2bf(w_nin[i]);
    }
    // fused: read feats once -> bf16 cast + per-channel sum/sumsq
    float s[8] = {}, q[8] = {};
    const int total = N_VOX * 64 / 8;
    for (int i = blockIdx.x * 256 + t; i < total; i += stride) {
        const float4* src = (const float4*)(feats + (size_t)i * 8);
        float4 f0 = src[0], f1 = src[1];
        float fv[8] = {f0.x, f0.y, f0.z, f0.w, f1.x, f1.y, f1.z, f1.w};
        union { uint4 u4; unsigned short u[8]; } r;
#pragma unroll
        for (int j = 0; j < 8; j++) {
            r.u[j] = f2bf(fv[j]);
            s[j] += fv[j]; q[j] += fv[j] * fv[j];
        }
        *(uint4*)(fRaw + (size_t)i * 8) = r.u4;
    }
    // lane's channel block = (lane&7)*8 (stride multiple of 8 chunks keeps it fixed)
#pragma unroll
    for (int j = 0; j < 8; j++) {
        s[j] += __shfl_xor(s[j], 8, 64); s[j] += __shfl_xor(s[j], 16, 64); s[j] += __shfl_xor(s[j], 32, 64);
        q[j] += __shfl_xor(q[j], 8, 64); q[j] += __shfl_xor(q[j], 16, 64); q[j] += __shfl_xor(q[j], 32, 64);
    }
    const int lane = t & 63;
    if (lane < 8) {
#pragma unroll
        for (int j = 0; j < 8; j++) {
            atomicAdd(&rs[lane * 8 + j], s[j]);
            atomicAdd(&rq[lane * 8 + j], q[j]);
        }
    }
    __syncthreads();
    if (t < 64) { atomicAdd(&s1sum[t], rs[t]); atomicAdd(&s1sq[t], rq[t]); }
}

// ---------------- inverse kernel-map ----------------
__global__ void build_inv_kernel(const int* __restrict__ sidx, const int* __restrict__ gidx,
                                 int* __restrict__ inv) {
    int k = blockIdx.y;
    int p = blockIdx.x * 256 + threadIdx.x;
    if (p < N_VOX) {
        int s = sidx[k * N_VOX + p];
        if (s < N_VOX) inv[k * N_VOX + s] = gidx[k * N_VOX + p];  // unique s per k -> no race
    }
}

// ---- prep1: BN1 folded weights: w1t[k][n][a] = bf16(w1[k][a][n]*sc1[a]); T1[k][n]=sh1@W1[k]
__global__ void prep1_kernel(const float* __restrict__ w1, const float* __restrict__ s1sum,
                             const float* __restrict__ s1sq, const float* __restrict__ g1,
                             const float* __restrict__ b1, unsigned short* __restrict__ w1t,
                             float* __restrict__ T1g) {
    __shared__ float lsc[64], lsh[64];
    const int t = threadIdx.x;
    if (t < 64) {
        float mean = s1sum[t] * (1.0f / N_VOX);
        float var  = s1sq[t] * (1.0f / N_VOX) - mean * mean;
        float sc   = g1[t] * rsqrtf(var + EPS_BN);
        lsc[t] = sc; lsh[t] = b1[t] - mean * sc;
    }
    __syncthreads();
    const int stride = gridDim.x * 256;
    for (int e = blockIdx.x * 256 + t; e < 27 * 8192; e += stride) {
        int k = e >> 13, idx = e & 8191;
        int a = idx >> 7, n = idx & 127;
        w1t[k * 8192 + n * 64 + a] = f2bf(w1[e] * lsc[a]);
    }
    int o = blockIdx.x * 256 + t;
    if (o < 27 * 128) {
        int k = o >> 7, n = o & 127;
        float sacc = 0.f;
        for (int a = 0; a < 64; a++) sacc += lsh[a] * w1[k * 8192 + a * 128 + n];
        T1g[o] = sacc;
    }
}

// ---- prep2: BN2 folded: w2t[k][n][a] = bf16(w2[k][a][n]*sc2[a]); T2[k][n]=sh2@W2[k]
__global__ void prep2_kernel(const float* __restrict__ w2, const float* __restrict__ s2sum,
                             const float* __restrict__ s2sq, const float* __restrict__ g2,
                             const float* __restrict__ b2, unsigned short* __restrict__ w2t,
                             float* __restrict__ T2g) {
    __shared__ float lsc[128], lsh[128];
    const int t = threadIdx.x;
    if (t < 128) {
        float mean = s2sum[t] * (1.0f / N_VOX);
        float var  = s2sq[t] * (1.0f / N_VOX) - mean * mean;
        float sc   = g2[t] * rsqrtf(var + EPS_BN);
        lsc[t] = sc; lsh[t] = b2[t] - mean * sc;
    }
    __syncthreads();
    const int stride = gridDim.x * 256;
    for (int e = blockIdx.x * 256 + t; e < 27 * 16384; e += stride) {
        int k = e >> 14, idx = e & 16383;
        int a = idx >> 7, n = idx & 127;
        w2t[k * 16384 + n * 128 + a] = f2bf(w2[e] * lsc[a]);
    }
    int o = blockIdx.x * 256 + t;
    if (o < 27 * 128) {
        int k = o >> 7, n = o & 127;
        float sacc = 0.f;
        for (int a = 0; a < 128; a++) sacc += lsh[a] * w2[k * 16384 + a * 128 + n];
        T2g[o] = sacc;
    }
}

// ---------------- conv1: h1[i] = sum_k BN1(f)[inv[k][i]] @ w1[k]  (64->128, bf16 out) ------
// R2-proven pipeline (2-deep dbuf, counted vmcnt(8), 2 barriers/iter, T2 swizzle). BN1
// folded (w1t pre-scaled, presence bias in epilogue). R5 fix: presence mask accumulated in
// VGPRs (rmq[4], 2 VALU ops/row/iter) -- NO DS ops between global_load_lds issues (R4's LDS
// atomicOr in the staging loop forced vmcnt drains: conv2 297->693us). One-time LDS handoff
// of the masks after the K-loop. BN2 stats fused into epilogue.
__global__ __launch_bounds__(256) void conv1_kernel(
    const unsigned short* __restrict__ fRaw, const unsigned short* __restrict__ w1t,
    const int* __restrict__ inv, const unsigned short* __restrict__ zp,
    const float* __restrict__ T1g, unsigned short* __restrict__ h1b,
    float* __restrict__ s2sum, float* __restrict__ s2sq) {
    __shared__ __align__(16) unsigned short sA[2][128 * 64];
    __shared__ __align__(16) unsigned short sB[2][128 * 64];
    __shared__ unsigned int presmask[128];
    __shared__ float s2s[128], s2q[128];
    const int t = threadIdx.x, lane = t & 63, w = t >> 6;
    const int v0 = blockIdx.x * 128;
    const int srow = w * 32;
    const int lrow = lane >> 3;
    const int lcol = (lane & 7) * 8;
    const int scol = lcol ^ (lrow * 8);
    const int m0 = (w & 1) * 64, n0 = (w >> 1) * 64;
    const int l16 = lane & 15, quad = lane >> 4;
    const int xs = l16 & 7;
    f32x4 acc[4][4] = {};
    unsigned int rmq[4] = {0u, 0u, 0u, 0u};  // presence bits for rows srow+q*8+lrow

    if (t < 128) { s2s[t] = 0.f; s2q[t] = 0.f; }
    __syncthreads();

    auto stage = [&](int k, int b) {
#pragma unroll
        for (int q = 0; q < 4; q++) {
            int rt = srow + q * 8 + lrow;
            int g = inv[k * N_VOX + v0 + rt];
            rmq[q] |= (g < N_VOX) ? (1u << k) : 0u;  // VGPR-only, no DS traffic
            const unsigned short* asrc = (g < N_VOX) ? (fRaw + (size_t)g * 64 + scol) : (zp + scol);
            ASYNC16(asrc, &sA[b][(srow + q * 8) * 64]);
            const unsigned short* bsrc = w1t + k * 8192 + rt * 64 + scol;
            ASYNC16(bsrc, &sB[b][(srow + q * 8) * 64]);
        }
    };

    stage(0, 0);
    for (int j = 0; j < 27; j++) {
        const int cb = j & 1;
        if (j + 1 < 27) {
            stage(j + 1, cb ^ 1);
            asm volatile("s_waitcnt vmcnt(8)" ::: "memory");
        } else {
            asm volatile("s_waitcnt vmcnt(0)" ::: "memory");
        }
        __builtin_amdgcn_sched_barrier(0);
        __builtin_amdgcn_s_barrier();
        __builtin_amdgcn_sched_barrier(0);
#pragma unroll
        for (int ks = 0; ks < 2; ks++) {
            const int cs = ((ks * 4 + quad) ^ xs) * 8;
            bf16x8 af[4], bfr[4];
#pragma unroll
            for (int mi = 0; mi < 4; mi++)
                af[mi] = *(const bf16x8*)&sA[cb][(m0 + mi * 16 + l16) * 64 + cs];
#pragma unroll
            for (int ni = 0; ni < 4; ni++)
                bfr[ni] = *(const bf16x8*)&sB[cb][(n0 + ni * 16 + l16) * 64 + cs];
            __builtin_amdgcn_s_setprio(1);
#pragma unroll
            for (int mi = 0; mi < 4; mi++)
#pragma unroll
                for (int ni = 0; ni < 4; ni++)
                    acc[mi][ni] = __builtin_amdgcn_mfma_f32_16x16x32_bf16(af[mi], bfr[ni], acc[mi][ni], 0, 0, 0);
            __builtin_amdgcn_s_setprio(0);
        }
        __builtin_amdgcn_sched_barrier(0);
        __builtin_amdgcn_s_barrier();
        __builtin_amdgcn_sched_barrier(0);
    }

    // ---- one-time mask handoff + epilogue: presence bias + fused BN2 stats + store ----
    if ((lane & 7) == 0) {
#pragma unroll
        for (int q = 0; q < 4; q++) presmask[srow + q * 8 + lrow] = rmq[q];
    }
    float* Tl = (float*)&sA[0][0];
    for (int idx = t; idx < 27 * 128; idx += 256) Tl[idx] = T1g[idx];
    __syncthreads();

    unsigned int rm[16];
#pragma unroll
    for (int mi = 0; mi < 4; mi++)
#pragma unroll
        for (int r = 0; r < 4; r++)
            rm[mi * 4 + r] = presmask[m0 + mi * 16 + quad * 4 + r];
    for (int k = 0; k < 27; k++) {
        float tk0 = Tl[k * 128 + n0 + l16];
        float tk1 = Tl[k * 128 + n0 + 16 + l16];
        float tk2 = Tl[k * 128 + n0 + 32 + l16];
        float tk3 = Tl[k * 128 + n0 + 48 + l16];
#pragma unroll
        for (int mi = 0; mi < 4; mi++)
#pragma unroll
            for (int r = 0; r < 4; r++)
                if ((rm[mi * 4 + r] >> k) & 1u) {
                    acc[mi][0][r] += tk0; acc[mi][1][r] += tk1;
                    acc[mi][2][r] += tk2; acc[mi][3][r] += tk3;
                }
    }
    float ps[4] = {}, pq[4] = {};
#pragma unroll
    for (int mi = 0; mi < 4; mi++)
#pragma unroll
        for (int r = 0; r < 4; r++) {
            int v = v0 + m0 + mi * 16 + quad * 4 + r;
            if (v < N_VOX) {
#pragma unroll
                for (int ni = 0; ni < 4; ni++) {
                    float x = acc[mi][ni][r];
                    ps[ni] += x; pq[ni] += x * x;
                    h1b[(size_t)v * 128 + n0 + ni * 16 + l16] = f2bf(x);
                }
            }
        }
#pragma unroll
    for (int ni = 0; ni < 4; ni++) {
        ps[ni] += __shfl_xor(ps[ni], 16, 64); ps[ni] += __shfl_xor(ps[ni], 32, 64);
        pq[ni] += __shfl_xor(pq[ni], 16, 64); pq[ni] += __shfl_xor(pq[ni], 32, 64);
    }
    if (lane < 16) {
#pragma unroll
        for (int ni = 0; ni < 4; ni++) {
            atomicAdd(&s2s[n0 + ni * 16 + lane], ps[ni]);
            atomicAdd(&s2q[n0 + ni * 16 + lane], pq[ni]);
        }
    }
    __syncthreads();
    if (t < 128) { atomicAdd(&s2sum[t], s2s[t]); atomicAdd(&s2sq[t], s2q[t]); }
}

// ------- conv2 + skip: out = sum_k BN2(h1)[inv[k]] @ w2[k] + fRaw @ w_nin (fp32 out) -------
// BN2 folded: gathers raw h1b, w2t pre-scaled by sc2, presence bias T2 in epilogue.
// 55 BK=64 iters: jj<54 -> (ko=jj>>1, kh=jj&1); jj==54 -> fused 1x1 skip.
// R5: VGPR presence accumulation (bit set on even j only), no DS ops in staging loop.
__global__ __launch_bounds__(256) void conv2_kernel(
    const unsigned short* __restrict__ h1n, const unsigned short* __restrict__ fRaw,
    const unsigned short* __restrict__ w2t, const unsigned short* __restrict__ w_nint,
    const int* __restrict__ inv, const unsigned short* __restrict__ zp,
    const float* __restrict__ T2g, float* __restrict__ out) {
    __shared__ __align__(16) unsigned short sA[2][128 * 64];
    __shared__ __align__(16) unsigned short sB[2][128 * 64];
    __shared__ unsigned int presmask[128];
    const int t = threadIdx.x, lane = t & 63, w = t >> 6;
    const int v0 = blockIdx.x * 128;
    const int srow = w * 32;
    const int lrow = lane >> 3;
    const int lcol = (lane & 7) * 8;
    const int scol = lcol ^ (lrow * 8);
    const int m0 = (w & 1) * 64, n0 = (w >> 1) * 64;
    const int l16 = lane & 15, quad = lane >> 4;
    const int xs = l16 & 7;
    f32x4 acc[4][4] = {};
    unsigned int rmq[4] = {0u, 0u, 0u, 0u};

    auto stage = [&](int j, int b) {
        if (j < 54) {
            const int ko = j >> 1;
            const int kh = (j & 1) * 64;
            const unsigned int bit = ((j & 1) == 0) ? 1u : 0u;  // count each ko once
#pragma unroll
            for (int q = 0; q < 4; q++) {
                int rt = srow + q * 8 + lrow;
                int g = inv[ko * N_VOX + v0 + rt];
                rmq[q] |= (g < N_VOX) ? (bit << ko) : 0u;  // VGPR-only
                const unsigned short* asrc = (g < N_VOX) ? (h1n + (size_t)g * 128 + kh + scol) : (zp + scol);
                ASYNC16(asrc, &sA[b][(srow + q * 8) * 64]);
                const unsigned short* bsrc = w2t + ko * 16384 + rt * 128 + kh + scol;
                ASYNC16(bsrc, &sB[b][(srow + q * 8) * 64]);
            }
        } else {
#pragma unroll
            for (int q = 0; q < 4; q++) {
                int rt = srow + q * 8 + lrow;
                int v = v0 + rt;
                const unsigned short* asrc = (v < N_VOX) ? (fRaw + (size_t)v * 64 + scol) : (zp + scol);
                ASYNC16(asrc, &sA[b][(srow + q * 8) * 64]);
                const unsigned short* bsrc = w_nint + rt * 64 + scol;
                ASYNC16(bsrc, &sB[b][(srow + q * 8) * 64]);
            }
        }
    };

    stage(0, 0);
    for (int jj = 0; jj < 55; jj++) {
        const int cb = jj & 1;
        if (jj + 1 < 55) {
            stage(jj + 1, cb ^ 1);
            asm volatile("s_waitcnt vmcnt(8)" ::: "memory");
        } else {
            asm volatile("s_waitcnt vmcnt(0)" ::: "memory");
        }
        __builtin_amdgcn_sched_barrier(0);
        __builtin_amdgcn_s_barrier();
        __builtin_amdgcn_sched_barrier(0);
#pragma unroll
        for (int ks = 0; ks < 2; ks++) {
            const int cs = ((ks * 4 + quad) ^ xs) * 8;
            bf16x8 af[4], bfr[4];
#pragma unroll
            for (int mi = 0; mi < 4; mi++)
                af[mi] = *(const bf16x8*)&sA[cb][(m0 + mi * 16 + l16) * 64 + cs];
#pragma unroll
            for (int ni = 0; ni < 4; ni++)
                bfr[ni] = *(const bf16x8*)&sB[cb][(n0 + ni * 16 + l16) * 64 + cs];
            __builtin_amdgcn_s_setprio(1);
#pragma unroll
            for (int mi = 0; mi < 4; mi++)
#pragma unroll
                for (int ni = 0; ni < 4; ni++)
                    acc[mi][ni] = __builtin_amdgcn_mfma_f32_16x16x32_bf16(af[mi], bfr[ni], acc[mi][ni], 0, 0, 0);
            __builtin_amdgcn_s_setprio(0);
        }
        __builtin_amdgcn_sched_barrier(0);
        __builtin_amdgcn_s_barrier();
        __builtin_amdgcn_sched_barrier(0);
    }

    // ---- one-time mask handoff + epilogue: presence bias (T2) + fp32 store ----
    if ((lane & 7) == 0) {
#pragma unroll
        for (int q = 0; q < 4; q++) presmask[srow + q * 8 + lrow] = rmq[q];
    }
    float* Tl = (float*)&sA[0][0];
    for (int idx = t; idx < 27 * 128; idx += 256) Tl[idx] = T2g[idx];
    __syncthreads();

    unsigned int rm[16];
#pragma unroll
    for (int mi = 0; mi < 4; mi++)
#pragma unroll
        for (int r = 0; r < 4; r++)
            rm[mi * 4 + r] = presmask[m0 + mi * 16 + quad * 4 + r];
    for (int k = 0; k < 27; k++) {
        float tk0 = Tl[k * 128 + n0 + l16];
        float tk1 = Tl[k * 128 + n0 + 16 + l16];
        float tk2 = Tl[k * 128 + n0 + 32 + l16];
        float tk3 = Tl[k * 128 + n0 + 48 + l16];
#pragma unroll
        for (int mi = 0; mi < 4; mi++)
#pragma unroll
            for (int r = 0; r < 4; r++)
                if ((rm[mi * 4 + r] >> k) & 1u) {
                    acc[mi][0][r] += tk0; acc[mi][1][r] += tk1;
                    acc[mi][2][r] += tk2; acc[mi][3][r] += tk3;
                }
    }
#pragma unroll
    for (int mi = 0; mi < 4; mi++)
#pragma unroll
        for (int r = 0; r < 4; r++) {
            int v = v0 + m0 + mi * 16 + quad * 4 + r;
            if (v < N_VOX) {
#pragma unroll
                for (int ni = 0; ni < 4; ni++)
                    out[(size_t)v * 128 + n0 + ni * 16 + l16] = acc[mi][ni][r];
            }
        }
}

extern "C" void kernel_launch(void* const* d_in, const int* in_sizes, int n_in,
                              void* d_out, int out_size, void* d_ws, size_t ws_size,
                              hipStream_t stream) {
    const float* feats = (const float*)d_in[0];
    const float* w1    = (const float*)d_in[1];
    const float* w2    = (const float*)d_in[2];
    const float* w_nin = (const float*)d_in[3];
    const float* g1    = (const float*)d_in[4];
    const float* b1    = (const float*)d_in[5];
    const float* g2    = (const float*)d_in[6];
    const float* b2    = (const float*)d_in[7];
    const int* gidx = (const int*)d_in[8];
    const int* sidx = (const int*)d_in[9];
    float* out = (float*)d_out;

    // workspace layout (~99.8 MB, 16B-aligned)
    char* ws = (char*)d_ws;
    int* inv               = (int*)(ws);                          // 21,600,512
    unsigned short* fRaw   = (unsigned short*)(ws + 21600512);    // 25,600,000
    unsigned short* h1b    = (unsigned short*)(ws + 47200512);    // 51,200,000
    unsigned short* w1t    = (unsigned short*)(ws + 98400512);    // 442,368
    unsigned short* w2t    = (unsigned short*)(ws + 98842880);    // 884,736
    unsigned short* w_nint = (unsigned short*)(ws + 99727616);    // 16,384
    float* T1g             = (float*)(ws + 99744000);             // 13,824
    float* T2g             = (float*)(ws + 99757824);             // 13,824
    float* stats           = (float*)(ws + 99771648);             // 1,536
    unsigned short* zp     = (unsigned short*)(ws + 99773184);    // 256 (zero page)
    float* s1sum = stats, *s1sq = stats + 64, *s2sum = stats + 128, *s2sq = stats + 256;

    hipMemsetAsync(stats, 0, 1536 + 256, stream);  // stats + zero page
    prep0_kernel<<<1024, 256, 0, stream>>>(feats, w_nin, inv, w_nint, fRaw, s1sum, s1sq);
    build_inv_kernel<<<dim3(782, 27), 256, 0, stream>>>(sidx, gidx, inv);
    prep1_kernel<<<512, 256, 0, stream>>>(w1, s1sum, s1sq, g1, b1, w1t, T1g);
    conv1_kernel<<<1563, 256, 0, stream>>>(fRaw, w1t, inv, zp, T1g, h1b, s2sum, s2sq);
    prep2_kernel<<<512, 256, 0, stream>>>(w2, s2sum, s2sq, g2, b2, w2t, T2g);
    conv2_kernel<<<1563, 256, 0, stream>>>(h1b, fRaw, w2t, w_nint, inv, zp, T2g, out);
}

// Round 6
// 956.044 us; speedup vs baseline: 1.4070x; 1.0162x over previous
//
#include <hip/hip_runtime.h>

#define N_VOX 200000
#define NPAD_INV (27 * N_VOX + 128)
#define EPS_BN 1e-5f

typedef __bf16 bf16x8 __attribute__((ext_vector_type(8)));
typedef float f32x4 __attribute__((ext_vector_type(4)));

__device__ __forceinline__ float bf2f(unsigned short u) {
    union { float f; unsigned int i; } x; x.i = ((unsigned int)u) << 16; return x.f;
}
__device__ __forceinline__ unsigned short f2bf(float f) {
    union { float f; unsigned int i; } x; x.f = f;
    unsigned int r = x.i + 0x7fffu + ((x.i >> 16) & 1u);  // RNE
    return (unsigned short)(r >> 16);
}

// async 16B/lane global->LDS; LDS dest = wave-uniform base + lane*16
#define ASYNC16(gsrc, ldst)                                                             \
    __builtin_amdgcn_global_load_lds(                                                   \
        (const __attribute__((address_space(1))) void*)(gsrc),                          \
        (__attribute__((address_space(3))) void*)(ldst), 16, 0, 0)

// ---------------- prep0: fill_inv + tr_wn + (feats -> fRaw cast + BN1 stats) -----------
__global__ void prep0_kernel(const float* __restrict__ feats, const float* __restrict__ w_nin,
                             int* __restrict__ inv, unsigned short* __restrict__ w_nint,
                             unsigned short* __restrict__ fRaw,
                             float* __restrict__ s1sum, float* __restrict__ s1sq) {
    __shared__ float rs[64], rq[64];
    const int t = threadIdx.x;
    if (t < 64) { rs[t] = 0.f; rq[t] = 0.f; }
    __syncthreads();
    const int stride = gridDim.x * 256;
    for (int i = blockIdx.x * 256 + t; i < NPAD_INV; i += stride) inv[i] = N_VOX;
    for (int i = blockIdx.x * 256 + t; i < 8192; i += stride) {
        int a = i >> 7, b = i & 127;
        w_nint[b * 64 + a] = f2bf(w_nin[i]);
    }
    float s[8] = {}, q[8] = {};
    const int total = N_VOX * 64 / 8;
    for (int i = blockIdx.x * 256 + t; i < total; i += stride) {
        const float4* src = (const float4*)(feats + (size_t)i * 8);
        float4 f0 = src[0], f1 = src[1];
        float fv[8] = {f0.x, f0.y, f0.z, f0.w, f1.x, f1.y, f1.z, f1.w};
        union { uint4 u4; unsigned short u[8]; } r;
#pragma unroll
        for (int j = 0; j < 8; j++) {
            r.u[j] = f2bf(fv[j]);
            s[j] += fv[j]; q[j] += fv[j] * fv[j];
        }
        *(uint4*)(fRaw + (size_t)i * 8) = r.u4;
    }
#pragma unroll
    for (int j = 0; j < 8; j++) {
        s[j] += __shfl_xor(s[j], 8, 64); s[j] += __shfl_xor(s[j], 16, 64); s[j] += __shfl_xor(s[j], 32, 64);
        q[j] += __shfl_xor(q[j], 8, 64); q[j] += __shfl_xor(q[j], 16, 64); q[j] += __shfl_xor(q[j], 32, 64);
    }
    const int lane = t & 63;
    if (lane < 8) {
#pragma unroll
        for (int j = 0; j < 8; j++) {
            atomicAdd(&rs[lane * 8 + j], s[j]);
            atomicAdd(&rq[lane * 8 + j], q[j]);
        }
    }
    __syncthreads();
    if (t < 64) { atomicAdd(&s1sum[t], rs[t]); atomicAdd(&s1sq[t], rq[t]); }
}

// ---------------- inverse kernel-map ----------------
__global__ void build_inv_kernel(const int* __restrict__ sidx, const int* __restrict__ gidx,
                                 int* __restrict__ inv) {
    int k = blockIdx.y;
    int p = blockIdx.x * 256 + threadIdx.x;
    if (p < N_VOX) {
        int s = sidx[k * N_VOX + p];
        if (s < N_VOX) inv[k * N_VOX + s] = gidx[k * N_VOX + p];  // unique s per k -> no race
    }
}

// ---- prep1: BN1 folded weights: w1t[k][n][a] = bf16(w1[k][a][n]*sc1[a]); T1[k][n]=sh1@W1[k]
__global__ void prep1_kernel(const float* __restrict__ w1, const float* __restrict__ s1sum,
                             const float* __restrict__ s1sq, const float* __restrict__ g1,
                             const float* __restrict__ b1, unsigned short* __restrict__ w1t,
                             float* __restrict__ T1g) {
    __shared__ float lsc[64], lsh[64];
    const int t = threadIdx.x;
    if (t < 64) {
        float mean = s1sum[t] * (1.0f / N_VOX);
        float var  = s1sq[t] * (1.0f / N_VOX) - mean * mean;
        float sc   = g1[t] * rsqrtf(var + EPS_BN);
        lsc[t] = sc; lsh[t] = b1[t] - mean * sc;
    }
    __syncthreads();
    const int stride = gridDim.x * 256;
    for (int e = blockIdx.x * 256 + t; e < 27 * 8192; e += stride) {
        int k = e >> 13, idx = e & 8191;
        int a = idx >> 7, n = idx & 127;
        w1t[k * 8192 + n * 64 + a] = f2bf(w1[e] * lsc[a]);
    }
    int o = blockIdx.x * 256 + t;
    if (o < 27 * 128) {
        int k = o >> 7, n = o & 127;
        float sacc = 0.f;
        for (int a = 0; a < 64; a++) sacc += lsh[a] * w1[k * 8192 + a * 128 + n];
        T1g[o] = sacc;
    }
}

// ---- prep2: BN2 folded: w2t[k][n][a] = bf16(w2[k][a][n]*sc2[a]); T2[k][n]=sh2@W2[k]
__global__ void prep2_kernel(const float* __restrict__ w2, const float* __restrict__ s2sum,
                             const float* __restrict__ s2sq, const float* __restrict__ g2,
                             const float* __restrict__ b2, unsigned short* __restrict__ w2t,
                             float* __restrict__ T2g) {
    __shared__ float lsc[128], lsh[128];
    const int t = threadIdx.x;
    if (t < 128) {
        float mean = s2sum[t] * (1.0f / N_VOX);
        float var  = s2sq[t] * (1.0f / N_VOX) - mean * mean;
        float sc   = g2[t] * rsqrtf(var + EPS_BN);
        lsc[t] = sc; lsh[t] = b2[t] - mean * sc;
    }
    __syncthreads();
    const int stride = gridDim.x * 256;
    for (int e = blockIdx.x * 256 + t; e < 27 * 16384; e += stride) {
        int k = e >> 14, idx = e & 16383;
        int a = idx >> 7, n = idx & 127;
        w2t[k * 16384 + n * 128 + a] = f2bf(w2[e] * lsc[a]);
    }
    int o = blockIdx.x * 256 + t;
    if (o < 27 * 128) {
        int k = o >> 7, n = o & 127;
        float sacc = 0.f;
        for (int a = 0; a < 128; a++) sacc += lsh[a] * w2[k * 16384 + a * 128 + n];
        T2g[o] = sacc;
    }
}

// ---------------- conv1: R2-EXACT structure (297us-proven pipeline scaled to 27 iters) ------
// Gathers raw fRaw with BN1-folded weights. NO presence/stats machinery in this kernel
// (R4/R5 showed in-conv presence work costs ~165us/conv; moved to biasstats_kernel).
__global__ __launch_bounds__(256) void conv1_kernel(
    const unsigned short* __restrict__ fRaw, const unsigned short* __restrict__ w1t,
    const int* __restrict__ inv, const unsigned short* __restrict__ zp,
    unsigned short* __restrict__ h1b) {
    __shared__ __align__(16) unsigned short sA[2][128 * 64];
    __shared__ __align__(16) unsigned short sB[2][128 * 64];
    const int t = threadIdx.x, lane = t & 63, w = t >> 6;
    const int v0 = blockIdx.x * 128;
    const int srow = w * 32;
    const int lrow = lane >> 3;
    const int lcol = (lane & 7) * 8;
    const int scol = lcol ^ (lrow * 8);
    const int m0 = (w & 1) * 64, n0 = (w >> 1) * 64;
    const int l16 = lane & 15, quad = lane >> 4;
    const int xs = l16 & 7;
    f32x4 acc[4][4] = {};

    auto stage = [&](int k, int b) {
#pragma unroll
        for (int q = 0; q < 4; q++) {
            int rt = srow + q * 8 + lrow;
            int g = inv[k * N_VOX + v0 + rt];
            const unsigned short* asrc = (g < N_VOX) ? (fRaw + (size_t)g * 64 + scol) : (zp + scol);
            ASYNC16(asrc, &sA[b][(srow + q * 8) * 64]);
            const unsigned short* bsrc = w1t + k * 8192 + rt * 64 + scol;
            ASYNC16(bsrc, &sB[b][(srow + q * 8) * 64]);
        }
    };

    stage(0, 0);
    for (int j = 0; j < 27; j++) {
        const int cb = j & 1;
        if (j + 1 < 27) {
            stage(j + 1, cb ^ 1);
            asm volatile("s_waitcnt vmcnt(8)" ::: "memory");
        } else {
            asm volatile("s_waitcnt vmcnt(0)" ::: "memory");
        }
        __builtin_amdgcn_sched_barrier(0);
        __builtin_amdgcn_s_barrier();
        __builtin_amdgcn_sched_barrier(0);
#pragma unroll
        for (int ks = 0; ks < 2; ks++) {
            const int cs = ((ks * 4 + quad) ^ xs) * 8;
            bf16x8 af[4], bfr[4];
#pragma unroll
            for (int mi = 0; mi < 4; mi++)
                af[mi] = *(const bf16x8*)&sA[cb][(m0 + mi * 16 + l16) * 64 + cs];
#pragma unroll
            for (int ni = 0; ni < 4; ni++)
                bfr[ni] = *(const bf16x8*)&sB[cb][(n0 + ni * 16 + l16) * 64 + cs];
            __builtin_amdgcn_s_setprio(1);
#pragma unroll
            for (int mi = 0; mi < 4; mi++)
#pragma unroll
                for (int ni = 0; ni < 4; ni++)
                    acc[mi][ni] = __builtin_amdgcn_mfma_f32_16x16x32_bf16(af[mi], bfr[ni], acc[mi][ni], 0, 0, 0);
            __builtin_amdgcn_s_setprio(0);
        }
        __builtin_amdgcn_sched_barrier(0);
        __builtin_amdgcn_s_barrier();
        __builtin_amdgcn_sched_barrier(0);
    }
#pragma unroll
    for (int mi = 0; mi < 4; mi++)
#pragma unroll
        for (int r = 0; r < 4; r++) {
            int v = v0 + m0 + mi * 16 + quad * 4 + r;
            if (v < N_VOX) {
#pragma unroll
                for (int ni = 0; ni < 4; ni++)
                    h1b[(size_t)v * 128 + n0 + ni * 16 + l16] = f2bf(acc[mi][ni][r]);
            }
        }
}

// --- biasstats: per voxel: mask32 = presence bits; h1b += bias1 (=sum_present T1[k]);
//     BN2 stats on biased h1. 16 threads/voxel (8 ch each). ~125MB streaming, cheap VALU.
__global__ __launch_bounds__(256) void biasstats_kernel(
    const int* __restrict__ inv, const float* __restrict__ T1g,
    unsigned short* __restrict__ h1b, unsigned int* __restrict__ mask32,
    float* __restrict__ s2sum, float* __restrict__ s2sq) {
    __shared__ float T1l[27 * 128];
    __shared__ float bs[128], bq[128];
    const int t = threadIdx.x;
    for (int i = t; i < 27 * 128; i += 256) T1l[i] = T1g[i];
    if (t < 128) { bs[t] = 0.f; bq[t] = 0.f; }
    __syncthreads();
    const int lane = t & 63;
    const int ch8 = (t & 15) * 8;
    const int vo = t >> 4;  // 16 voxels per block-iter
    float ps[8] = {}, pq[8] = {};
    for (int v0 = blockIdx.x * 16; v0 < N_VOX; v0 += gridDim.x * 16) {
        int v = v0 + vo;
        bool act = v < N_VOX;
        unsigned int m = 0u;
        float b1[8] = {};
        for (int k = 0; k < 27; k++) {
            int g = act ? inv[k * N_VOX + v] : N_VOX;
            if (g < N_VOX) {
                m |= (1u << k);
#pragma unroll
                for (int j = 0; j < 8; j++) b1[j] += T1l[k * 128 + ch8 + j];
            }
        }
        if (act) {
            if ((t & 15) == 0) mask32[v] = m;
            union { uint4 q; unsigned short u[8]; } hv;
            hv.q = *(const uint4*)(h1b + (size_t)v * 128 + ch8);
#pragma unroll
            for (int j = 0; j < 8; j++) {
                float x = bf2f(hv.u[j]) + b1[j];
                hv.u[j] = f2bf(x);
                ps[j] += x; pq[j] += x * x;
            }
            *(uint4*)(h1b + (size_t)v * 128 + ch8) = hv.q;
        }
    }
#pragma unroll
    for (int j = 0; j < 8; j++) {
        ps[j] += __shfl_xor(ps[j], 16, 64); ps[j] += __shfl_xor(ps[j], 32, 64);
        pq[j] += __shfl_xor(pq[j], 16, 64); pq[j] += __shfl_xor(pq[j], 32, 64);
    }
    if (lane < 16) {
#pragma unroll
        for (int j = 0; j < 8; j++) {
            atomicAdd(&bs[ch8 + j], ps[j]);
            atomicAdd(&bq[ch8 + j], pq[j]);
        }
    }
    __syncthreads();
    if (t < 128) { atomicAdd(&s2sum[t], bs[t]); atomicAdd(&s2sq[t], bq[t]); }
}

// ------- conv2 + skip: out = sum_k BN2(h1)[inv[k]] @ w2[k] + fRaw @ w_nin (fp32 out) -------
// R2-EXACT hot loop. Epilogue adds presence bias from PRECOMPUTED mask32 (one coalesced
// dword/voxel) + T2 table staged in LDS -- no in-stage tracking, no handoff.
__global__ __launch_bounds__(256) void conv2_kernel(
    const unsigned short* __restrict__ h1n, const unsigned short* __restrict__ fRaw,
    const unsigned short* __restrict__ w2t, const unsigned short* __restrict__ w_nint,
    const int* __restrict__ inv, const unsigned short* __restrict__ zp,
    const unsigned int* __restrict__ mask32, const float* __restrict__ T2g,
    float* __restrict__ out) {
    __shared__ __align__(16) unsigned short sA[2][128 * 64];
    __shared__ __align__(16) unsigned short sB[2][128 * 64];
    __shared__ unsigned int pm[128];
    const int t = threadIdx.x, lane = t & 63, w = t >> 6;
    const int v0 = blockIdx.x * 128;
    const int srow = w * 32;
    const int lrow = lane >> 3;
    const int lcol = (lane & 7) * 8;
    const int scol = lcol ^ (lrow * 8);
    const int m0 = (w & 1) * 64, n0 = (w >> 1) * 64;
    const int l16 = lane & 15, quad = lane >> 4;
    const int xs = l16 & 7;
    f32x4 acc[4][4] = {};

    auto stage = [&](int j, int b) {
        if (j < 54) {
            const int ko = j >> 1;
            const int kh = (j & 1) * 64;
#pragma unroll
            for (int q = 0; q < 4; q++) {
                int rt = srow + q * 8 + lrow;
                int g = inv[ko * N_VOX + v0 + rt];
                const unsigned short* asrc = (g < N_VOX) ? (h1n + (size_t)g * 128 + kh + scol) : (zp + scol);
                ASYNC16(asrc, &sA[b][(srow + q * 8) * 64]);
                const unsigned short* bsrc = w2t + ko * 16384 + rt * 128 + kh + scol;
                ASYNC16(bsrc, &sB[b][(srow + q * 8) * 64]);
            }
        } else {
#pragma unroll
            for (int q = 0; q < 4; q++) {
                int rt = srow + q * 8 + lrow;
                int v = v0 + rt;
                const unsigned short* asrc = (v < N_VOX) ? (fRaw + (size_t)v * 64 + scol) : (zp + scol);
                ASYNC16(asrc, &sA[b][(srow + q * 8) * 64]);
                const unsigned short* bsrc = w_nint + rt * 64 + scol;
                ASYNC16(bsrc, &sB[b][(srow + q * 8) * 64]);
            }
        }
    };

    stage(0, 0);
    for (int jj = 0; jj < 55; jj++) {
        const int cb = jj & 1;
        if (jj + 1 < 55) {
            stage(jj + 1, cb ^ 1);
            asm volatile("s_waitcnt vmcnt(8)" ::: "memory");
        } else {
            asm volatile("s_waitcnt vmcnt(0)" ::: "memory");
        }
        __builtin_amdgcn_sched_barrier(0);
        __builtin_amdgcn_s_barrier();
        __builtin_amdgcn_sched_barrier(0);
#pragma unroll
        for (int ks = 0; ks < 2; ks++) {
            const int cs = ((ks * 4 + quad) ^ xs) * 8;
            bf16x8 af[4], bfr[4];
#pragma unroll
            for (int mi = 0; mi < 4; mi++)
                af[mi] = *(const bf16x8*)&sA[cb][(m0 + mi * 16 + l16) * 64 + cs];
#pragma unroll
            for (int ni = 0; ni < 4; ni++)
                bfr[ni] = *(const bf16x8*)&sB[cb][(n0 + ni * 16 + l16) * 64 + cs];
            __builtin_amdgcn_s_setprio(1);
#pragma unroll
            for (int mi = 0; mi < 4; mi++)
#pragma unroll
                for (int ni = 0; ni < 4; ni++)
                    acc[mi][ni] = __builtin_amdgcn_mfma_f32_16x16x32_bf16(af[mi], bfr[ni], acc[mi][ni], 0, 0, 0);
            __builtin_amdgcn_s_setprio(0);
        }
        __builtin_amdgcn_sched_barrier(0);
        __builtin_amdgcn_s_barrier();
        __builtin_amdgcn_sched_barrier(0);
    }

    // ---- epilogue: presence bias from precomputed mask32 + fp32 store ----
    if (t < 128) pm[t] = (v0 + t < N_VOX) ? mask32[v0 + t] : 0u;
    float* Tl = (float*)&sA[0][0];
    for (int idx = t; idx < 27 * 128; idx += 256) Tl[idx] = T2g[idx];
    __syncthreads();

    unsigned int rm[16];
#pragma unroll
    for (int mi = 0; mi < 4; mi++)
#pragma unroll
        for (int r = 0; r < 4; r++)
            rm[mi * 4 + r] = pm[m0 + mi * 16 + quad * 4 + r];
    for (int k = 0; k < 27; k++) {
        float tk0 = Tl[k * 128 + n0 + l16];
        float tk1 = Tl[k * 128 + n0 + 16 + l16];
        float tk2 = Tl[k * 128 + n0 + 32 + l16];
        float tk3 = Tl[k * 128 + n0 + 48 + l16];
#pragma unroll
        for (int mi = 0; mi < 4; mi++)
#pragma unroll
            for (int r = 0; r < 4; r++)
                if ((rm[mi * 4 + r] >> k) & 1u) {
                    acc[mi][0][r] += tk0; acc[mi][1][r] += tk1;
                    acc[mi][2][r] += tk2; acc[mi][3][r] += tk3;
                }
    }
#pragma unroll
    for (int mi = 0; mi < 4; mi++)
#pragma unroll
        for (int r = 0; r < 4; r++) {
            int v = v0 + m0 + mi * 16 + quad * 4 + r;
            if (v < N_VOX) {
#pragma unroll
                for (int ni = 0; ni < 4; ni++)
                    out[(size_t)v * 128 + n0 + ni * 16 + l16] = acc[mi][ni][r];
            }
        }
}

extern "C" void kernel_launch(void* const* d_in, const int* in_sizes, int n_in,
                              void* d_out, int out_size, void* d_ws, size_t ws_size,
                              hipStream_t stream) {
    const float* feats = (const float*)d_in[0];
    const float* w1    = (const float*)d_in[1];
    const float* w2    = (const float*)d_in[2];
    const float* w_nin = (const float*)d_in[3];
    const float* g1    = (const float*)d_in[4];
    const float* b1    = (const float*)d_in[5];
    const float* g2    = (const float*)d_in[6];
    const float* b2    = (const float*)d_in[7];
    const int* gidx = (const int*)d_in[8];
    const int* sidx = (const int*)d_in[9];
    float* out = (float*)d_out;

    // workspace layout (~100.6 MB, 16B-aligned)
    char* ws = (char*)d_ws;
    int* inv               = (int*)(ws);                          // 21,600,512
    unsigned short* fRaw   = (unsigned short*)(ws + 21600512);    // 25,600,000
    unsigned short* h1b    = (unsigned short*)(ws + 47200512);    // 51,200,000
    unsigned short* w1t    = (unsigned short*)(ws + 98400512);    // 442,368
    unsigned short* w2t    = (unsigned short*)(ws + 98842880);    // 884,736
    unsigned short* w_nint = (unsigned short*)(ws + 99727616);    // 16,384
    float* T1g             = (float*)(ws + 99744000);             // 13,824
    float* T2g             = (float*)(ws + 99757824);             // 13,824
    unsigned int* mask32   = (unsigned int*)(ws + 99771648);      // 800,000
    float* stats           = (float*)(ws + 100571648);            // 1,536
    unsigned short* zp     = (unsigned short*)(ws + 100573184);   // 256 (zero page)
    float* s1sum = stats, *s1sq = stats + 64, *s2sum = stats + 128, *s2sq = stats + 256;

    hipMemsetAsync(stats, 0, 1536 + 256, stream);  // stats + zero page
    prep0_kernel<<<1024, 256, 0, stream>>>(feats, w_nin, inv, w_nint, fRaw, s1sum, s1sq);
    build_inv_kernel<<<dim3(782, 27), 256, 0, stream>>>(sidx, gidx, inv);
    prep1_kernel<<<512, 256, 0, stream>>>(w1, s1sum, s1sq, g1, b1, w1t, T1g);
    conv1_kernel<<<1563, 256, 0, stream>>>(fRaw, w1t, inv, zp, h1b);
    biasstats_kernel<<<782, 256, 0, stream>>>(inv, T1g, h1b, mask32, s2sum, s2sq);
    prep2_kernel<<<512, 256, 0, stream>>>(w2, s2sum, s2sq, g2, b2, w2t, T2g);
    conv2_kernel<<<1563, 256, 0, stream>>>(h1b, fRaw, w2t, w_nint, inv, zp, mask32, T2g, out);
}

// Round 7
// 745.908 us; speedup vs baseline: 1.8034x; 1.2817x over previous
//
#include <hip/hip_runtime.h>

#define N_VOX 200000
#define NPAD_INV (27 * N_VOX + 128)
#define EPS_BN 1e-5f

typedef __bf16 bf16x8 __attribute__((ext_vector_type(8)));
typedef float f32x4 __attribute__((ext_vector_type(4)));

__device__ __forceinline__ float bf2f(unsigned short u) {
    union { float f; unsigned int i; } x; x.i = ((unsigned int)u) << 16; return x.f;
}
__device__ __forceinline__ unsigned short f2bf(float f) {
    union { float f; unsigned int i; } x; x.f = f;
    unsigned int r = x.i + 0x7fffu + ((x.i >> 16) & 1u);  // RNE
    return (unsigned short)(r >> 16);
}

// async 16B/lane global->LDS; LDS dest = wave-uniform base + lane*16
#define ASYNC16(gsrc, ldst)                                                             \
    __builtin_amdgcn_global_load_lds(                                                   \
        (const __attribute__((address_space(1))) void*)(gsrc),                          \
        (__attribute__((address_space(3))) void*)(ldst), 16, 0, 0)

// ---- prep0: fill_inv + tr_w1 + tr_w2 + tr_wn + (feats -> fRaw cast + BN1 stats) ----
// Consolidates 6 former dispatches. All plain (no BN folding -- R4-R6 showed presence-bias
// machinery costs ~170us/conv; normalize-before-gather makes presence handling free).
__global__ void prep0_kernel(const float* __restrict__ feats, const float* __restrict__ w1,
                             const float* __restrict__ w2, const float* __restrict__ w_nin,
                             int* __restrict__ inv, unsigned short* __restrict__ w1t,
                             unsigned short* __restrict__ w2t, unsigned short* __restrict__ w_nint,
                             unsigned short* __restrict__ fRaw,
                             float* __restrict__ s1sum, float* __restrict__ s1sq) {
    __shared__ float rs[64], rq[64];
    const int t = threadIdx.x;
    if (t < 64) { rs[t] = 0.f; rq[t] = 0.f; }
    __syncthreads();
    const int stride = gridDim.x * 256;
    const int gid = blockIdx.x * 256 + t;
    for (int i = gid; i < NPAD_INV; i += stride) inv[i] = N_VOX;
    for (int i = gid; i < 8192; i += stride) {
        int a = i >> 7, b = i & 127;
        w_nint[b * 64 + a] = f2bf(w_nin[i]);
    }
    for (int e = gid; e < 27 * 8192; e += stride) {
        int k = e >> 13, idx = e & 8191;
        int a = idx >> 7, b = idx & 127;
        w1t[k * 8192 + b * 64 + a] = f2bf(w1[e]);
    }
    for (int e = gid; e < 27 * 16384; e += stride) {
        int k = e >> 14, idx = e & 16383;
        int a = idx >> 7, b = idx & 127;
        w2t[k * 16384 + b * 128 + a] = f2bf(w2[e]);
    }
    // fused: read feats once -> bf16 cast + per-channel sum/sumsq
    float s[8] = {}, q[8] = {};
    const int total = N_VOX * 64 / 8;
    for (int i = gid; i < total; i += stride) {
        const float4* src = (const float4*)(feats + (size_t)i * 8);
        float4 f0 = src[0], f1 = src[1];
        float fv[8] = {f0.x, f0.y, f0.z, f0.w, f1.x, f1.y, f1.z, f1.w};
        union { uint4 u4; unsigned short u[8]; } r;
#pragma unroll
        for (int j = 0; j < 8; j++) {
            r.u[j] = f2bf(fv[j]);
            s[j] += fv[j]; q[j] += fv[j] * fv[j];
        }
        *(uint4*)(fRaw + (size_t)i * 8) = r.u4;
    }
    // thread's channel block = (t&7)*8 (stride is a multiple of 8 chunks)
#pragma unroll
    for (int j = 0; j < 8; j++) {
        s[j] += __shfl_xor(s[j], 8, 64); s[j] += __shfl_xor(s[j], 16, 64); s[j] += __shfl_xor(s[j], 32, 64);
        q[j] += __shfl_xor(q[j], 8, 64); q[j] += __shfl_xor(q[j], 16, 64); q[j] += __shfl_xor(q[j], 32, 64);
    }
    const int lane = t & 63;
    if (lane < 8) {
#pragma unroll
        for (int j = 0; j < 8; j++) {
            atomicAdd(&rs[lane * 8 + j], s[j]);
            atomicAdd(&rq[lane * 8 + j], q[j]);
        }
    }
    __syncthreads();
    if (t < 64) { atomicAdd(&s1sum[t], rs[t]); atomicAdd(&s1sq[t], rq[t]); }
}

// ---- prepbn: build_inv scatter + norm1 (fA = bf16(BN1(fRaw))) ----
__global__ void prepbn_kernel(const int* __restrict__ sidx, const int* __restrict__ gidx,
                              int* __restrict__ inv, const unsigned short* __restrict__ fRaw,
                              const float* __restrict__ s1sum, const float* __restrict__ s1sq,
                              const float* __restrict__ g1, const float* __restrict__ b1,
                              unsigned short* __restrict__ fA) {
    __shared__ float sc[64], sh[64];
    const int t = threadIdx.x;
    if (t < 64) {
        float mean = s1sum[t] * (1.0f / N_VOX);
        float var  = s1sq[t] * (1.0f / N_VOX) - mean * mean;
        float s    = g1[t] * rsqrtf(var + EPS_BN);
        sc[t] = s; sh[t] = b1[t] - mean * s;
    }
    __syncthreads();
    const int stride = gridDim.x * 256;
    const int gid = blockIdx.x * 256 + t;
    // build inverse kernel-map (unique s per k -> no race)
    for (int k = 0; k < 27; k++)
        for (int p = gid; p < N_VOX; p += stride) {
            int s = sidx[k * N_VOX + p];
            if (s < N_VOX) inv[k * N_VOX + s] = gidx[k * N_VOX + p];
        }
    // norm1: fA = BN1 applied to fRaw
    const int total = N_VOX * 64 / 8;
    for (int i = gid; i < total; i += stride) {
        int cb = (i * 8) & 63;
        union { uint4 q; unsigned short u[8]; } v, a;
        v.q = *(const uint4*)(fRaw + (size_t)i * 8);
#pragma unroll
        for (int j = 0; j < 8; j++) a.u[j] = f2bf(bf2f(v.u[j]) * sc[cb + j] + sh[cb + j]);
        *(uint4*)(fA + (size_t)i * 8) = a.q;
    }
}

// ---------------- BN2 stats (R2-exact) ----------------
__global__ void stats2_kernel(const unsigned short* __restrict__ h1b,
                              float* __restrict__ sum, float* __restrict__ sq) {
    int t = threadIdx.x; int c = t & 127; int rg = t >> 7;
    float s = 0.f, q = 0.f;
    for (int row = blockIdx.x * 2 + rg; row < N_VOX; row += gridDim.x * 2) {
        float x = bf2f(h1b[(size_t)row * 128 + c]);
        s += x; q += x * x;
    }
    __shared__ float red[4][128];
    red[rg][c] = s; red[2 + rg][c] = q;
    __syncthreads();
    if (t < 128) atomicAdd(&sum[t], red[0][t] + red[1][t]);
    else { int cc = t - 128; atomicAdd(&sq[cc], red[2][cc] + red[3][cc]); }
}

// ---------------- norm2: h1b = bf16(BN2(h1b)) in-place (R2-exact) ----------------
__global__ void norm2_kernel(unsigned short* __restrict__ h1b, const float* __restrict__ ssum,
                             const float* __restrict__ ssq, const float* __restrict__ gamma,
                             const float* __restrict__ beta) {
    __shared__ float sc[128], sh[128];
    int t = threadIdx.x;
    if (t < 128) {
        float mean = ssum[t] * (1.0f / N_VOX);
        float var  = ssq[t] * (1.0f / N_VOX) - mean * mean;
        float s    = gamma[t] * rsqrtf(var + EPS_BN);
        sc[t] = s; sh[t] = beta[t] - mean * s;
    }
    __syncthreads();
    const int total = N_VOX * 128 / 8;
    int i = blockIdx.x * 256 + t;
    if (i >= total) return;
    int cb = (i * 8) & 127;
    union { uint4 q; unsigned short u[8]; } v;
    v.q = *(const uint4*)(h1b + (size_t)i * 8);
#pragma unroll
    for (int j = 0; j < 8; j++) v.u[j] = f2bf(bf2f(v.u[j]) * sc[cb + j] + sh[cb + j]);
    *(uint4*)(h1b + (size_t)i * 8) = v.q;
}

// ---------------- conv1: h1[i] = sum_k fA[inv[k][i]] @ w1[k]  (64->128, bf16 out) ----------
// R2-EXACT (297us-proven pipeline): 2-deep dbuf, counted vmcnt(8), 2 barriers/iter,
// T2 XOR swizzle (bank conflicts 0). NO extra machinery (R4-R6 lesson).
__global__ __launch_bounds__(256) void conv1_kernel(
    const unsigned short* __restrict__ fA, const unsigned short* __restrict__ w1t,
    const int* __restrict__ inv, const unsigned short* __restrict__ zp,
    unsigned short* __restrict__ h1b) {
    __shared__ __align__(16) unsigned short sA[2][128 * 64];
    __shared__ __align__(16) unsigned short sB[2][128 * 64];
    const int t = threadIdx.x, lane = t & 63, w = t >> 6;
    const int v0 = blockIdx.x * 128;
    const int srow = w * 32;
    const int lrow = lane >> 3;
    const int lcol = (lane & 7) * 8;
    const int scol = lcol ^ (lrow * 8);
    const int m0 = (w & 1) * 64, n0 = (w >> 1) * 64;
    const int l16 = lane & 15, quad = lane >> 4;
    const int xs = l16 & 7;
    f32x4 acc[4][4] = {};

    auto stage = [&](int k, int b) {
#pragma unroll
        for (int q = 0; q < 4; q++) {
            int rt = srow + q * 8 + lrow;
            int g = inv[k * N_VOX + v0 + rt];
            const unsigned short* asrc = (g < N_VOX) ? (fA + (size_t)g * 64 + scol) : (zp + scol);
            ASYNC16(asrc, &sA[b][(srow + q * 8) * 64]);
            const unsigned short* bsrc = w1t + k * 8192 + rt * 64 + scol;
            ASYNC16(bsrc, &sB[b][(srow + q * 8) * 64]);
        }
    };

    stage(0, 0);
    for (int j = 0; j < 27; j++) {
        const int cb = j & 1;
        if (j + 1 < 27) {
            stage(j + 1, cb ^ 1);
            asm volatile("s_waitcnt vmcnt(8)" ::: "memory");
        } else {
            asm volatile("s_waitcnt vmcnt(0)" ::: "memory");
        }
        __builtin_amdgcn_sched_barrier(0);
        __builtin_amdgcn_s_barrier();
        __builtin_amdgcn_sched_barrier(0);
#pragma unroll
        for (int ks = 0; ks < 2; ks++) {
            const int cs = ((ks * 4 + quad) ^ xs) * 8;
            bf16x8 af[4], bfr[4];
#pragma unroll
            for (int mi = 0; mi < 4; mi++)
                af[mi] = *(const bf16x8*)&sA[cb][(m0 + mi * 16 + l16) * 64 + cs];
#pragma unroll
            for (int ni = 0; ni < 4; ni++)
                bfr[ni] = *(const bf16x8*)&sB[cb][(n0 + ni * 16 + l16) * 64 + cs];
            __builtin_amdgcn_s_setprio(1);
#pragma unroll
            for (int mi = 0; mi < 4; mi++)
#pragma unroll
                for (int ni = 0; ni < 4; ni++)
                    acc[mi][ni] = __builtin_amdgcn_mfma_f32_16x16x32_bf16(af[mi], bfr[ni], acc[mi][ni], 0, 0, 0);
            __builtin_amdgcn_s_setprio(0);
        }
        __builtin_amdgcn_sched_barrier(0);
        __builtin_amdgcn_s_barrier();
        __builtin_amdgcn_sched_barrier(0);
    }
#pragma unroll
    for (int mi = 0; mi < 4; mi++)
#pragma unroll
        for (int r = 0; r < 4; r++) {
            int v = v0 + m0 + mi * 16 + quad * 4 + r;
            if (v < N_VOX) {
#pragma unroll
                for (int ni = 0; ni < 4; ni++)
                    h1b[(size_t)v * 128 + n0 + ni * 16 + l16] = f2bf(acc[mi][ni][r]);
            }
        }
}

// ------- conv2 + skip: out[i] = sum_k h1n[inv[k][i]] @ w2[k] + fRaw[i] @ w_nin (fp32 out) ----
// R2-EXACT. 55 BK=64 iters: jj<54 -> (ko=jj>>1, kh=jj&1); jj==54 -> fused 1x1 skip.
__global__ __launch_bounds__(256) void conv2_kernel(
    const unsigned short* __restrict__ h1n, const unsigned short* __restrict__ fRaw,
    const unsigned short* __restrict__ w2t, const unsigned short* __restrict__ w_nint,
    const int* __restrict__ inv, const unsigned short* __restrict__ zp,
    float* __restrict__ out) {
    __shared__ __align__(16) unsigned short sA[2][128 * 64];
    __shared__ __align__(16) unsigned short sB[2][128 * 64];
    const int t = threadIdx.x, lane = t & 63, w = t >> 6;
    const int v0 = blockIdx.x * 128;
    const int srow = w * 32;
    const int lrow = lane >> 3;
    const int lcol = (lane & 7) * 8;
    const int scol = lcol ^ (lrow * 8);
    const int m0 = (w & 1) * 64, n0 = (w >> 1) * 64;
    const int l16 = lane & 15, quad = lane >> 4;
    const int xs = l16 & 7;
    f32x4 acc[4][4] = {};

    auto stage = [&](int j, int b) {
        if (j < 54) {
            const int ko = j >> 1;
            const int kh = (j & 1) * 64;
#pragma unroll
            for (int q = 0; q < 4; q++) {
                int rt = srow + q * 8 + lrow;
                int g = inv[ko * N_VOX + v0 + rt];
                const unsigned short* asrc = (g < N_VOX) ? (h1n + (size_t)g * 128 + kh + scol) : (zp + scol);
                ASYNC16(asrc, &sA[b][(srow + q * 8) * 64]);
                const unsigned short* bsrc = w2t + ko * 16384 + rt * 128 + kh + scol;
                ASYNC16(bsrc, &sB[b][(srow + q * 8) * 64]);
            }
        } else {
#pragma unroll
            for (int q = 0; q < 4; q++) {
                int rt = srow + q * 8 + lrow;
                int v = v0 + rt;
                const unsigned short* asrc = (v < N_VOX) ? (fRaw + (size_t)v * 64 + scol) : (zp + scol);
                ASYNC16(asrc, &sA[b][(srow + q * 8) * 64]);
                const unsigned short* bsrc = w_nint + rt * 64 + scol;
                ASYNC16(bsrc, &sB[b][(srow + q * 8) * 64]);
            }
        }
    };

    stage(0, 0);
    for (int jj = 0; jj < 55; jj++) {
        const int cb = jj & 1;
        if (jj + 1 < 55) {
            stage(jj + 1, cb ^ 1);
            asm volatile("s_waitcnt vmcnt(8)" ::: "memory");
        } else {
            asm volatile("s_waitcnt vmcnt(0)" ::: "memory");
        }
        __builtin_amdgcn_sched_barrier(0);
        __builtin_amdgcn_s_barrier();
        __builtin_amdgcn_sched_barrier(0);
#pragma unroll
        for (int ks = 0; ks < 2; ks++) {
            const int cs = ((ks * 4 + quad) ^ xs) * 8;
            bf16x8 af[4], bfr[4];
#pragma unroll
            for (int mi = 0; mi < 4; mi++)
                af[mi] = *(const bf16x8*)&sA[cb][(m0 + mi * 16 + l16) * 64 + cs];
#pragma unroll
            for (int ni = 0; ni < 4; ni++)
                bfr[ni] = *(const bf16x8*)&sB[cb][(n0 + ni * 16 + l16) * 64 + cs];
            __builtin_amdgcn_s_setprio(1);
#pragma unroll
            for (int mi = 0; mi < 4; mi++)
#pragma unroll
                for (int ni = 0; ni < 4; ni++)
                    acc[mi][ni] = __builtin_amdgcn_mfma_f32_16x16x32_bf16(af[mi], bfr[ni], acc[mi][ni], 0, 0, 0);
            __builtin_amdgcn_s_setprio(0);
        }
        __builtin_amdgcn_sched_barrier(0);
        __builtin_amdgcn_s_barrier();
        __builtin_amdgcn_sched_barrier(0);
    }
#pragma unroll
    for (int mi = 0; mi < 4; mi++)
#pragma unroll
        for (int r = 0; r < 4; r++) {
            int v = v0 + m0 + mi * 16 + quad * 4 + r;
            if (v < N_VOX) {
#pragma unroll
                for (int ni = 0; ni < 4; ni++)
                    out[(size_t)v * 128 + n0 + ni * 16 + l16] = acc[mi][ni][r];
            }
        }
}

extern "C" void kernel_launch(void* const* d_in, const int* in_sizes, int n_in,
                              void* d_out, int out_size, void* d_ws, size_t ws_size,
                              hipStream_t stream) {
    const float* feats = (const float*)d_in[0];
    const float* w1    = (const float*)d_in[1];
    const float* w2    = (const float*)d_in[2];
    const float* w_nin = (const float*)d_in[3];
    const float* g1    = (const float*)d_in[4];
    const float* b1    = (const float*)d_in[5];
    const float* g2    = (const float*)d_in[6];
    const float* b2    = (const float*)d_in[7];
    const int* gidx = (const int*)d_in[8];
    const int* sidx = (const int*)d_in[9];
    float* out = (float*)d_out;

    // workspace layout (~125.3 MB, all 16B-aligned; proven-safe size from R0-R2)
    char* ws = (char*)d_ws;
    int* inv               = (int*)(ws);                          // 21,600,512
    unsigned short* fRaw   = (unsigned short*)(ws + 21600512);    // 25,600,000
    unsigned short* fA     = (unsigned short*)(ws + 47200512);    // 25,600,000
    unsigned short* h1b    = (unsigned short*)(ws + 72800512);    // 51,200,000
    unsigned short* w1t    = (unsigned short*)(ws + 124000512);   // 442,368
    unsigned short* w2t    = (unsigned short*)(ws + 124442880);   // 884,736
    unsigned short* w_nint = (unsigned short*)(ws + 125327616);   // 16,384
    float* stats           = (float*)(ws + 125344000);            // 1,536
    unsigned short* zp     = (unsigned short*)(ws + 125345536);   // 256 (zero page)
    float* s1sum = stats, *s1sq = stats + 64, *s2sum = stats + 128, *s2sq = stats + 256;

    hipMemsetAsync(stats, 0, 1536 + 256, stream);  // stats + zero page
    prep0_kernel<<<1024, 256, 0, stream>>>(feats, w1, w2, w_nin, inv, w1t, w2t, w_nint,
                                           fRaw, s1sum, s1sq);
    prepbn_kernel<<<1024, 256, 0, stream>>>(sidx, gidx, inv, fRaw, s1sum, s1sq, g1, b1, fA);
    conv1_kernel<<<1563, 256, 0, stream>>>(fA, w1t, inv, zp, h1b);
    stats2_kernel<<<512, 256, 0, stream>>>(h1b, s2sum, s2sq);
    norm2_kernel<<<12500, 256, 0, stream>>>(h1b, s2sum, s2sq, g2, b2);
    conv2_kernel<<<1563, 256, 0, stream>>>(h1b, fRaw, w2t, w_nint, inv, zp, out);
}

// Round 8
// 701.361 us; speedup vs baseline: 1.9180x; 1.0635x over previous
//
#include <hip/hip_runtime.h>

#define N_VOX 200000
#define NPAD_INV (27 * N_VOX + 128)
#define EPS_BN 1e-5f

typedef __bf16 bf16x8 __attribute__((ext_vector_type(8)));
typedef float f32x4 __attribute__((ext_vector_type(4)));

__device__ __forceinline__ float bf2f(unsigned short u) {
    union { float f; unsigned int i; } x; x.i = ((unsigned int)u) << 16; return x.f;
}
__device__ __forceinline__ unsigned short f2bf(float f) {
    union { float f; unsigned int i; } x; x.f = f;
    unsigned int r = x.i + 0x7fffu + ((x.i >> 16) & 1u);  // RNE
    return (unsigned short)(r >> 16);
}

// async 16B/lane global->LDS; LDS dest = wave-uniform base + lane*16
#define ASYNC16(gsrc, ldst)                                                             \
    __builtin_amdgcn_global_load_lds(                                                   \
        (const __attribute__((address_space(1))) void*)(gsrc),                          \
        (__attribute__((address_space(3))) void*)(ldst), 16, 0, 0)

// ---- prep0: fill_inv + tr_w1 + tr_w2 + tr_wn + (feats -> fRaw cast + BN1 stats) ----
__global__ void prep0_kernel(const float* __restrict__ feats, const float* __restrict__ w1,
                             const float* __restrict__ w2, const float* __restrict__ w_nin,
                             int* __restrict__ inv, unsigned short* __restrict__ w1t,
                             unsigned short* __restrict__ w2t, unsigned short* __restrict__ w_nint,
                             unsigned short* __restrict__ fRaw,
                             float* __restrict__ s1sum, float* __restrict__ s1sq) {
    __shared__ float rs[64], rq[64];
    const int t = threadIdx.x;
    if (t < 64) { rs[t] = 0.f; rq[t] = 0.f; }
    __syncthreads();
    const int stride = gridDim.x * 256;
    const int gid = blockIdx.x * 256 + t;
    for (int i = gid; i < NPAD_INV; i += stride) inv[i] = N_VOX;
    for (int i = gid; i < 8192; i += stride) {
        int a = i >> 7, b = i & 127;
        w_nint[b * 64 + a] = f2bf(w_nin[i]);
    }
    for (int e = gid; e < 27 * 8192; e += stride) {
        int k = e >> 13, idx = e & 8191;
        int a = idx >> 7, b = idx & 127;
        w1t[k * 8192 + b * 64 + a] = f2bf(w1[e]);
    }
    for (int e = gid; e < 27 * 16384; e += stride) {
        int k = e >> 14, idx = e & 16383;
        int a = idx >> 7, b = idx & 127;
        w2t[k * 16384 + b * 128 + a] = f2bf(w2[e]);
    }
    float s[8] = {}, q[8] = {};
    const int total = N_VOX * 64 / 8;
    for (int i = gid; i < total; i += stride) {
        const float4* src = (const float4*)(feats + (size_t)i * 8);
        float4 f0 = src[0], f1 = src[1];
        float fv[8] = {f0.x, f0.y, f0.z, f0.w, f1.x, f1.y, f1.z, f1.w};
        union { uint4 u4; unsigned short u[8]; } r;
#pragma unroll
        for (int j = 0; j < 8; j++) {
            r.u[j] = f2bf(fv[j]);
            s[j] += fv[j]; q[j] += fv[j] * fv[j];
        }
        *(uint4*)(fRaw + (size_t)i * 8) = r.u4;
    }
#pragma unroll
    for (int j = 0; j < 8; j++) {
        s[j] += __shfl_xor(s[j], 8, 64); s[j] += __shfl_xor(s[j], 16, 64); s[j] += __shfl_xor(s[j], 32, 64);
        q[j] += __shfl_xor(q[j], 8, 64); q[j] += __shfl_xor(q[j], 16, 64); q[j] += __shfl_xor(q[j], 32, 64);
    }
    const int lane = t & 63;
    if (lane < 8) {
#pragma unroll
        for (int j = 0; j < 8; j++) {
            atomicAdd(&rs[lane * 8 + j], s[j]);
            atomicAdd(&rq[lane * 8 + j], q[j]);
        }
    }
    __syncthreads();
    if (t < 64) { atomicAdd(&s1sum[t], rs[t]); atomicAdd(&s1sq[t], rq[t]); }
}

// ---- prepbn: build_inv scatter (with per-k valid-prefix early exit) + norm1 ----
// Valid (sidx,gidx) entries are a PREFIX per k (rest padded with N_VOX). 27 binary
// searches (t<27, ~18 cached probes each) find e[k]; the scatter loop then skips
// ~55% of the 172.8MB sidx/gidx read that is pure padding.
__global__ void prepbn_kernel(const int* __restrict__ sidx, const int* __restrict__ gidx,
                              int* __restrict__ inv, const unsigned short* __restrict__ fRaw,
                              const float* __restrict__ s1sum, const float* __restrict__ s1sq,
                              const float* __restrict__ g1, const float* __restrict__ b1,
                              unsigned short* __restrict__ fA) {
    __shared__ float sc[64], sh[64];
    __shared__ int ek[27];
    const int t = threadIdx.x;
    if (t < 64) {
        float mean = s1sum[t] * (1.0f / N_VOX);
        float var  = s1sq[t] * (1.0f / N_VOX) - mean * mean;
        float s    = g1[t] * rsqrtf(var + EPS_BN);
        sc[t] = s; sh[t] = b1[t] - mean * s;
    }
    if (t < 27) {  // binary search: first p with sidx[k][p] == N_VOX
        int lo = 0, hi = N_VOX;
        while (lo < hi) {
            int mid = (lo + hi) >> 1;
            if (sidx[t * N_VOX + mid] == N_VOX) hi = mid; else lo = mid + 1;
        }
        ek[t] = lo;
    }
    __syncthreads();
    const int stride = gridDim.x * 256;
    const int gid = blockIdx.x * 256 + t;
    for (int k = 0; k < 27; k++) {
        const int e = ek[k];
        for (int p = gid; p < e; p += stride) {
            int s = sidx[k * N_VOX + p];
            inv[k * N_VOX + s] = gidx[k * N_VOX + p];  // unique s per k -> no race
        }
    }
    // norm1: fA = BN1 applied to fRaw
    const int total = N_VOX * 64 / 8;
    for (int i = gid; i < total; i += stride) {
        int cb = (i * 8) & 63;
        union { uint4 q; unsigned short u[8]; } v, a;
        v.q = *(const uint4*)(fRaw + (size_t)i * 8);
#pragma unroll
        for (int j = 0; j < 8; j++) a.u[j] = f2bf(bf2f(v.u[j]) * sc[cb + j] + sh[cb + j]);
        *(uint4*)(fA + (size_t)i * 8) = a.q;
    }
}

// ---------------- norm2: h1b = bf16(BN2(h1b)) in-place (R2-exact) ----------------
__global__ void norm2_kernel(unsigned short* __restrict__ h1b, const float* __restrict__ ssum,
                             const float* __restrict__ ssq, const float* __restrict__ gamma,
                             const float* __restrict__ beta) {
    __shared__ float sc[128], sh[128];
    int t = threadIdx.x;
    if (t < 128) {
        float mean = ssum[t] * (1.0f / N_VOX);
        float var  = ssq[t] * (1.0f / N_VOX) - mean * mean;
        float s    = gamma[t] * rsqrtf(var + EPS_BN);
        sc[t] = s; sh[t] = beta[t] - mean * s;
    }
    __syncthreads();
    const int total = N_VOX * 128 / 8;
    int i = blockIdx.x * 256 + t;
    if (i >= total) return;
    int cb = (i * 8) & 127;
    union { uint4 q; unsigned short u[8]; } v;
    v.q = *(const uint4*)(h1b + (size_t)i * 8);
#pragma unroll
    for (int j = 0; j < 8; j++) v.u[j] = f2bf(bf2f(v.u[j]) * sc[cb + j] + sh[cb + j]);
    *(uint4*)(h1b + (size_t)i * 8) = v.q;
}

// ---------------- conv1: h1[i] = sum_k fA[inv[k][i]] @ w1[k]  (64->128, bf16 out) ----------
// R2-EXACT hot loop (297us-proven pipeline). Epilogue additionally accumulates BN2 stats
// (straight-line FMAs + shuffle + LDS reduce + 256 global atomics -- NOT the R4-R6 poison,
// which was the divergent bias loop / in-stage DS ops). Replaces the stats2 kernel.
__global__ __launch_bounds__(256) void conv1_kernel(
    const unsigned short* __restrict__ fA, const unsigned short* __restrict__ w1t,
    const int* __restrict__ inv, const unsigned short* __restrict__ zp,
    unsigned short* __restrict__ h1b, float* __restrict__ s2sum, float* __restrict__ s2sq) {
    __shared__ __align__(16) unsigned short sA[2][128 * 64];
    __shared__ __align__(16) unsigned short sB[2][128 * 64];
    __shared__ float s2s[128], s2q[128];
    const int t = threadIdx.x, lane = t & 63, w = t >> 6;
    const int v0 = blockIdx.x * 128;
    const int srow = w * 32;
    const int lrow = lane >> 3;
    const int lcol = (lane & 7) * 8;
    const int scol = lcol ^ (lrow * 8);
    const int m0 = (w & 1) * 64, n0 = (w >> 1) * 64;
    const int l16 = lane & 15, quad = lane >> 4;
    const int xs = l16 & 7;
    f32x4 acc[4][4] = {};

    if (t < 128) { s2s[t] = 0.f; s2q[t] = 0.f; }

    auto stage = [&](int k, int b) {
#pragma unroll
        for (int q = 0; q < 4; q++) {
            int rt = srow + q * 8 + lrow;
            int g = inv[k * N_VOX + v0 + rt];
            const unsigned short* asrc = (g < N_VOX) ? (fA + (size_t)g * 64 + scol) : (zp + scol);
            ASYNC16(asrc, &sA[b][(srow + q * 8) * 64]);
            const unsigned short* bsrc = w1t + k * 8192 + rt * 64 + scol;
            ASYNC16(bsrc, &sB[b][(srow + q * 8) * 64]);
        }
    };

    stage(0, 0);
    for (int j = 0; j < 27; j++) {
        const int cb = j & 1;
        if (j + 1 < 27) {
            stage(j + 1, cb ^ 1);
            asm volatile("s_waitcnt vmcnt(8)" ::: "memory");
        } else {
            asm volatile("s_waitcnt vmcnt(0)" ::: "memory");
        }
        __builtin_amdgcn_sched_barrier(0);
        __builtin_amdgcn_s_barrier();
        __builtin_amdgcn_sched_barrier(0);
#pragma unroll
        for (int ks = 0; ks < 2; ks++) {
            const int cs = ((ks * 4 + quad) ^ xs) * 8;
            bf16x8 af[4], bfr[4];
#pragma unroll
            for (int mi = 0; mi < 4; mi++)
                af[mi] = *(const bf16x8*)&sA[cb][(m0 + mi * 16 + l16) * 64 + cs];
#pragma unroll
            for (int ni = 0; ni < 4; ni++)
                bfr[ni] = *(const bf16x8*)&sB[cb][(n0 + ni * 16 + l16) * 64 + cs];
            __builtin_amdgcn_s_setprio(1);
#pragma unroll
            for (int mi = 0; mi < 4; mi++)
#pragma unroll
                for (int ni = 0; ni < 4; ni++)
                    acc[mi][ni] = __builtin_amdgcn_mfma_f32_16x16x32_bf16(af[mi], bfr[ni], acc[mi][ni], 0, 0, 0);
            __builtin_amdgcn_s_setprio(0);
        }
        __builtin_amdgcn_sched_barrier(0);
        __builtin_amdgcn_s_barrier();
        __builtin_amdgcn_sched_barrier(0);
    }

    // ---- epilogue: bf16 store + fused BN2 stats ----
    float ps[4] = {}, pq[4] = {};
#pragma unroll
    for (int mi = 0; mi < 4; mi++)
#pragma unroll
        for (int r = 0; r < 4; r++) {
            int v = v0 + m0 + mi * 16 + quad * 4 + r;
            if (v < N_VOX) {
#pragma unroll
                for (int ni = 0; ni < 4; ni++) {
                    float x = acc[mi][ni][r];
                    ps[ni] += x; pq[ni] += x * x;
                    h1b[(size_t)v * 128 + n0 + ni * 16 + l16] = f2bf(x);
                }
            }
        }
#pragma unroll
    for (int ni = 0; ni < 4; ni++) {
        ps[ni] += __shfl_xor(ps[ni], 16, 64); ps[ni] += __shfl_xor(ps[ni], 32, 64);
        pq[ni] += __shfl_xor(pq[ni], 16, 64); pq[ni] += __shfl_xor(pq[ni], 32, 64);
    }
    if (lane < 16) {
#pragma unroll
        for (int ni = 0; ni < 4; ni++) {
            atomicAdd(&s2s[n0 + ni * 16 + lane], ps[ni]);
            atomicAdd(&s2q[n0 + ni * 16 + lane], pq[ni]);
        }
    }
    __syncthreads();
    if (t < 128) { atomicAdd(&s2sum[t], s2s[t]); atomicAdd(&s2sq[t], s2q[t]); }
}

// ------- conv2 + skip: out[i] = sum_k h1n[inv[k][i]] @ w2[k] + fRaw[i] @ w_nin (fp32 out) ----
// R2-EXACT hot loop. Epilogue uses NON-TEMPORAL stores for `out` (write-once, never
// re-read) to stop evicting h1 lines from L2/L3 (FETCH_SIZE shows h1 re-fetched ~4.6x).
__global__ __launch_bounds__(256) void conv2_kernel(
    const unsigned short* __restrict__ h1n, const unsigned short* __restrict__ fRaw,
    const unsigned short* __restrict__ w2t, const unsigned short* __restrict__ w_nint,
    const int* __restrict__ inv, const unsigned short* __restrict__ zp,
    float* __restrict__ out) {
    __shared__ __align__(16) unsigned short sA[2][128 * 64];
    __shared__ __align__(16) unsigned short sB[2][128 * 64];
    const int t = threadIdx.x, lane = t & 63, w = t >> 6;
    const int v0 = blockIdx.x * 128;
    const int srow = w * 32;
    const int lrow = lane >> 3;
    const int lcol = (lane & 7) * 8;
    const int scol = lcol ^ (lrow * 8);
    const int m0 = (w & 1) * 64, n0 = (w >> 1) * 64;
    const int l16 = lane & 15, quad = lane >> 4;
    const int xs = l16 & 7;
    f32x4 acc[4][4] = {};

    auto stage = [&](int j, int b) {
        if (j < 54) {
            const int ko = j >> 1;
            const int kh = (j & 1) * 64;
#pragma unroll
            for (int q = 0; q < 4; q++) {
                int rt = srow + q * 8 + lrow;
                int g = inv[ko * N_VOX + v0 + rt];
                const unsigned short* asrc = (g < N_VOX) ? (h1n + (size_t)g * 128 + kh + scol) : (zp + scol);
                ASYNC16(asrc, &sA[b][(srow + q * 8) * 64]);
                const unsigned short* bsrc = w2t + ko * 16384 + rt * 128 + kh + scol;
                ASYNC16(bsrc, &sB[b][(srow + q * 8) * 64]);
            }
        } else {
#pragma unroll
            for (int q = 0; q < 4; q++) {
                int rt = srow + q * 8 + lrow;
                int v = v0 + rt;
                const unsigned short* asrc = (v < N_VOX) ? (fRaw + (size_t)v * 64 + scol) : (zp + scol);
                ASYNC16(asrc, &sA[b][(srow + q * 8) * 64]);
                const unsigned short* bsrc = w_nint + rt * 64 + scol;
                ASYNC16(bsrc, &sB[b][(srow + q * 8) * 64]);
            }
        }
    };

    stage(0, 0);
    for (int jj = 0; jj < 55; jj++) {
        const int cb = jj & 1;
        if (jj + 1 < 55) {
            stage(jj + 1, cb ^ 1);
            asm volatile("s_waitcnt vmcnt(8)" ::: "memory");
        } else {
            asm volatile("s_waitcnt vmcnt(0)" ::: "memory");
        }
        __builtin_amdgcn_sched_barrier(0);
        __builtin_amdgcn_s_barrier();
        __builtin_amdgcn_sched_barrier(0);
#pragma unroll
        for (int ks = 0; ks < 2; ks++) {
            const int cs = ((ks * 4 + quad) ^ xs) * 8;
            bf16x8 af[4], bfr[4];
#pragma unroll
            for (int mi = 0; mi < 4; mi++)
                af[mi] = *(const bf16x8*)&sA[cb][(m0 + mi * 16 + l16) * 64 + cs];
#pragma unroll
            for (int ni = 0; ni < 4; ni++)
                bfr[ni] = *(const bf16x8*)&sB[cb][(n0 + ni * 16 + l16) * 64 + cs];
            __builtin_amdgcn_s_setprio(1);
#pragma unroll
            for (int mi = 0; mi < 4; mi++)
#pragma unroll
                for (int ni = 0; ni < 4; ni++)
                    acc[mi][ni] = __builtin_amdgcn_mfma_f32_16x16x32_bf16(af[mi], bfr[ni], acc[mi][ni], 0, 0, 0);
            __builtin_amdgcn_s_setprio(0);
        }
        __builtin_amdgcn_sched_barrier(0);
        __builtin_amdgcn_s_barrier();
        __builtin_amdgcn_sched_barrier(0);
    }
#pragma unroll
    for (int mi = 0; mi < 4; mi++)
#pragma unroll
        for (int r = 0; r < 4; r++) {
            int v = v0 + m0 + mi * 16 + quad * 4 + r;
            if (v < N_VOX) {
#pragma unroll
                for (int ni = 0; ni < 4; ni++)
                    __builtin_nontemporal_store(acc[mi][ni][r],
                                                &out[(size_t)v * 128 + n0 + ni * 16 + l16]);
            }
        }
}

extern "C" void kernel_launch(void* const* d_in, const int* in_sizes, int n_in,
                              void* d_out, int out_size, void* d_ws, size_t ws_size,
                              hipStream_t stream) {
    const float* feats = (const float*)d_in[0];
    const float* w1    = (const float*)d_in[1];
    const float* w2    = (const float*)d_in[2];
    const float* w_nin = (const float*)d_in[3];
    const float* g1    = (const float*)d_in[4];
    const float* b1    = (const float*)d_in[5];
    const float* g2    = (const float*)d_in[6];
    const float* b2    = (const float*)d_in[7];
    const int* gidx = (const int*)d_in[8];
    const int* sidx = (const int*)d_in[9];
    float* out = (float*)d_out;

    // workspace layout (~125.3 MB, all 16B-aligned; proven-safe size from R0-R2)
    char* ws = (char*)d_ws;
    int* inv               = (int*)(ws);                          // 21,600,512
    unsigned short* fRaw   = (unsigned short*)(ws + 21600512);    // 25,600,000
    unsigned short* fA     = (unsigned short*)(ws + 47200512);    // 25,600,000
    unsigned short* h1b    = (unsigned short*)(ws + 72800512);    // 51,200,000
    unsigned short* w1t    = (unsigned short*)(ws + 124000512);   // 442,368
    unsigned short* w2t    = (unsigned short*)(ws + 124442880);   // 884,736
    unsigned short* w_nint = (unsigned short*)(ws + 125327616);   // 16,384
    float* stats           = (float*)(ws + 125344000);            // 1,536
    unsigned short* zp     = (unsigned short*)(ws + 125345536);   // 256 (zero page)
    float* s1sum = stats, *s1sq = stats + 64, *s2sum = stats + 128, *s2sq = stats + 256;

    hipMemsetAsync(stats, 0, 1536 + 256, stream);  // stats + zero page
    prep0_kernel<<<1024, 256, 0, stream>>>(feats, w1, w2, w_nin, inv, w1t, w2t, w_nint,
                                           fRaw, s1sum, s1sq);
    prepbn_kernel<<<1024, 256, 0, stream>>>(sidx, gidx, inv, fRaw, s1sum, s1sq, g1, b1, fA);
    conv1_kernel<<<1563, 256, 0, stream>>>(fA, w1t, inv, zp, h1b, s2sum, s2sq);
    norm2_kernel<<<12500, 256, 0, stream>>>(h1b, s2sum, s2sq, g2, b2);
    conv2_kernel<<<1563, 256, 0, stream>>>(h1b, fRaw, w2t, w_nint, inv, zp, out);
}